// Round 3
// baseline (1847.280 us; speedup 1.0000x reference)
//
#include <hip/hip_runtime.h>
#include <hip/hip_bf16.h>

// Qwen3.5 attention block: T=4096, H=2048, NH=16, NKV=2, HD=256, ROT=64
// bf16 MFMA (16x16x32) with fp32 accumulate; precision-critical intermediates
// kept fp32 or split into bf16 hi/lo pairs (packed ushort2 in 4B slots).

#define T_SZ 4096
#define H_SZ 2048
#define NH_SZ 16
#define NKV_SZ 2
#define HD_SZ 256
#define ATT_SCALE 0.0625f   // HD^-0.5
#define EPS_ 1e-6f

typedef __attribute__((ext_vector_type(8))) short bf16x8;   // 8 bf16 = 4 VGPRs
typedef __attribute__((ext_vector_type(4))) float f32x4;

#define MFMA16(a, b, c) __builtin_amdgcn_mfma_f32_16x16x32_bf16((a), (b), (c), 0, 0, 0)

__device__ __forceinline__ void async16(const void* g, void* l) {
  __builtin_amdgcn_global_load_lds((const __attribute__((address_space(1))) void*)g,
                                   (__attribute__((address_space(3))) void*)l,
                                   16, 0, 0);
}

__device__ __forceinline__ float to_f(float x) { return x; }
__device__ __forceinline__ float to_f(__hip_bfloat16 x) { return __bfloat162float(x); }

union BfBits { __hip_bfloat16 h; unsigned short u; };

__device__ __forceinline__ unsigned short bf16_bits(__hip_bfloat16 h) {
  BfBits t; t.h = h; return t.u;
}

__device__ __forceinline__ unsigned pack_hilo(float v) {
  __hip_bfloat16 hi = __float2bfloat16(v);
  float rem = v - __bfloat162float(hi);
  __hip_bfloat16 lo = __float2bfloat16(rem);
  return (unsigned)bf16_bits(hi) | ((unsigned)bf16_bits(lo) << 16);
}

// ---------------------------------------------------------------- cast hidden
__global__ __launch_bounds__(256) void cast_f32_bf16(const float* __restrict__ in,
                                                     __hip_bfloat16* __restrict__ out,
                                                     int n4) {
  int i = blockIdx.x * 256 + threadIdx.x;
  if (i >= n4) return;
  float4 v = ((const float4*)in)[i];
  union { __hip_bfloat16 h[4]; uint2 u; } t;
  t.h[0] = __float2bfloat16(v.x);
  t.h[1] = __float2bfloat16(v.y);
  t.h[2] = __float2bfloat16(v.z);
  t.h[3] = __float2bfloat16(v.w);
  ((uint2*)out)[i] = t.u;
}

// ------------------------------------------------------- transpose (+cast bf16)
template <typename TIN>
__global__ __launch_bounds__(256) void transpose_cast(const TIN* __restrict__ in,
                                                      __hip_bfloat16* __restrict__ out,
                                                      int R, int C) {
  __shared__ TIN tile[32][33];
  int c0 = blockIdx.x * 32, r0 = blockIdx.y * 32;
  int tx = threadIdx.x & 31, ty = threadIdx.x >> 5;
#pragma unroll
  for (int i = 0; i < 32; i += 8)
    tile[ty + i][tx] = in[(long)(r0 + ty + i) * C + c0 + tx];
  __syncthreads();
#pragma unroll
  for (int i = 0; i < 32; i += 8)
    out[(long)(c0 + ty + i) * R + r0 + tx] = __float2bfloat16(to_f(tile[tx][ty + i]));
}

// transpose fp32 -> bf16 hi + bf16 lo (for Wo split)
__global__ __launch_bounds__(256) void transpose_split(const float* __restrict__ in,
                                                       __hip_bfloat16* __restrict__ oh,
                                                       __hip_bfloat16* __restrict__ ol,
                                                       int R, int C) {
  __shared__ float tile[32][33];
  int c0 = blockIdx.x * 32, r0 = blockIdx.y * 32;
  int tx = threadIdx.x & 31, ty = threadIdx.x >> 5;
#pragma unroll
  for (int i = 0; i < 32; i += 8)
    tile[ty + i][tx] = in[(long)(r0 + ty + i) * C + c0 + tx];
  __syncthreads();
#pragma unroll
  for (int i = 0; i < 32; i += 8) {
    float v = tile[tx][ty + i];
    __hip_bfloat16 hi = __float2bfloat16(v);
    __hip_bfloat16 lo = __float2bfloat16(v - __bfloat162float(hi));
    long idx = (long)(c0 + ty + i) * R + r0 + tx;
    oh[idx] = hi;
    ol[idx] = lo;
  }
}

// ------------------------------------------------------------------ GEMM (B^T)
// C[M][N] = A[M][K] @ BT[N][K]^T. 128x128 tile, BK=32, 4 waves, 4x4 frags/wave.
template <int OUTF32>
__global__ __launch_bounds__(256) void gemm_bt(const __hip_bfloat16* __restrict__ A,
                                               const __hip_bfloat16* __restrict__ BT,
                                               void* __restrict__ Cp,
                                               int M, int N, int K) {
  __shared__ __align__(16) __hip_bfloat16 As[128 * 32];
  __shared__ __align__(16) __hip_bfloat16 Bs[128 * 32];
  const int tid = threadIdx.x;
  const int wid = tid >> 6, lane = tid & 63;
  const int lo = lane & 15, quad = lane >> 4;
  const long m0 = (long)blockIdx.y * 128, n0 = (long)blockIdx.x * 128;
  const int wm = (wid >> 1) * 64, wn = (wid & 1) * 64;
  const f32x4 z4 = {0.f, 0.f, 0.f, 0.f};
  f32x4 acc[4][4];
#pragma unroll
  for (int i = 0; i < 4; ++i)
#pragma unroll
    for (int j = 0; j < 4; ++j) acc[i][j] = z4;

  const int cf0 = tid, cf1 = 256 + tid;
  const int r0_ = cf0 >> 2, c0_ = (cf0 & 3) * 8;
  const int r1_ = cf1 >> 2, c1_ = (cf1 & 3) * 8;
  const __hip_bfloat16* a0 = A + (m0 + r0_) * K + c0_;
  const __hip_bfloat16* a1 = A + (m0 + r1_) * K + c1_;
  const __hip_bfloat16* b0 = BT + (n0 + r0_) * K + c0_;
  const __hip_bfloat16* b1 = BT + (n0 + r1_) * K + c1_;

  for (int k0 = 0; k0 < K; k0 += 32) {
    async16(a0 + k0, As + cf0 * 8);
    async16(a1 + k0, As + cf1 * 8);
    async16(b0 + k0, Bs + cf0 * 8);
    async16(b1 + k0, Bs + cf1 * 8);
    __syncthreads();
    bf16x8 af[4], bfv[4];
#pragma unroll
    for (int i = 0; i < 4; ++i)
      af[i] = *(const bf16x8*)(As + (wm + i * 16 + lo) * 32 + quad * 8);
#pragma unroll
    for (int i = 0; i < 4; ++i)
      bfv[i] = *(const bf16x8*)(Bs + (wn + i * 16 + lo) * 32 + quad * 8);
#pragma unroll
    for (int i = 0; i < 4; ++i)
#pragma unroll
      for (int j = 0; j < 4; ++j) acc[i][j] = MFMA16(af[i], bfv[j], acc[i][j]);
    __syncthreads();
  }
#pragma unroll
  for (int i = 0; i < 4; ++i)
#pragma unroll
    for (int j = 0; j < 4; ++j)
#pragma unroll
      for (int r = 0; r < 4; ++r) {
        long row = m0 + wm + i * 16 + quad * 4 + r;
        long col = n0 + wn + j * 16 + lo;
        float v = acc[i][j][r];
        if (OUTF32)
          ((float*)Cp)[row * N + col] = v;
        else
          ((__hip_bfloat16*)Cp)[row * N + col] = __float2bfloat16(v);
      }
}

// ------------------------------------------- Wq GEMM with q(fp32)/gate(bf16) split
__global__ __launch_bounds__(256) void gemm_qg(const __hip_bfloat16* __restrict__ A,
                                               const __hip_bfloat16* __restrict__ BT,
                                               float* __restrict__ qout,
                                               __hip_bfloat16* __restrict__ gate,
                                               int M, int N, int K) {
  __shared__ __align__(16) __hip_bfloat16 As[128 * 32];
  __shared__ __align__(16) __hip_bfloat16 Bs[128 * 32];
  const int tid = threadIdx.x;
  const int wid = tid >> 6, lane = tid & 63;
  const int lo = lane & 15, quad = lane >> 4;
  const long m0 = (long)blockIdx.y * 128, n0 = (long)blockIdx.x * 128;
  const int wm = (wid >> 1) * 64, wn = (wid & 1) * 64;
  const f32x4 z4 = {0.f, 0.f, 0.f, 0.f};
  f32x4 acc[4][4];
#pragma unroll
  for (int i = 0; i < 4; ++i)
#pragma unroll
    for (int j = 0; j < 4; ++j) acc[i][j] = z4;

  const int cf0 = tid, cf1 = 256 + tid;
  const int r0_ = cf0 >> 2, c0_ = (cf0 & 3) * 8;
  const int r1_ = cf1 >> 2, c1_ = (cf1 & 3) * 8;
  const __hip_bfloat16* a0 = A + (m0 + r0_) * K + c0_;
  const __hip_bfloat16* a1 = A + (m0 + r1_) * K + c1_;
  const __hip_bfloat16* b0 = BT + (n0 + r0_) * K + c0_;
  const __hip_bfloat16* b1 = BT + (n0 + r1_) * K + c1_;

  for (int k0 = 0; k0 < K; k0 += 32) {
    async16(a0 + k0, As + cf0 * 8);
    async16(a1 + k0, As + cf1 * 8);
    async16(b0 + k0, Bs + cf0 * 8);
    async16(b1 + k0, Bs + cf1 * 8);
    __syncthreads();
    bf16x8 af[4], bfv[4];
#pragma unroll
    for (int i = 0; i < 4; ++i)
      af[i] = *(const bf16x8*)(As + (wm + i * 16 + lo) * 32 + quad * 8);
#pragma unroll
    for (int i = 0; i < 4; ++i)
      bfv[i] = *(const bf16x8*)(Bs + (wn + i * 16 + lo) * 32 + quad * 8);
#pragma unroll
    for (int i = 0; i < 4; ++i)
#pragma unroll
      for (int j = 0; j < 4; ++j) acc[i][j] = MFMA16(af[i], bfv[j], acc[i][j]);
    __syncthreads();
  }
#pragma unroll
  for (int i = 0; i < 4; ++i)
#pragma unroll
    for (int j = 0; j < 4; ++j)
#pragma unroll
      for (int r = 0; r < 4; ++r) {
        long row = m0 + wm + i * 16 + quad * 4 + r;  // token t
        long col = n0 + wn + j * 16 + lo;            // n in [0,8192)
        int head = (int)(col >> 9), c = (int)(col & 511);
        float v = acc[i][j][r];
        if (c < 256)
          qout[(row * NH_SZ + head) * 256 + c] = v;
        else
          gate[(row * NH_SZ + head) * 256 + (c - 256)] = __float2bfloat16(v);
      }
}

// ------------------------- RMSNorm + RoPE from fp32, write packed hi/lo in-place
__global__ __launch_bounds__(256) void norm_rope_pack(float* __restrict__ qbuf,
                                                      float* __restrict__ kbuf,
                                                      const int* __restrict__ pos,
                                                      const float* __restrict__ qw,
                                                      const float* __restrict__ kw) {
  const int t = blockIdx.x, h = blockIdx.y, d = threadIdx.x;
  __shared__ float buf[256];
  __shared__ float red[4];
  float* ptr;
  const float* w;
  if (h < NH_SZ) {
    ptr = qbuf + ((long)t * NH_SZ + h) * 256;
    w = qw;
  } else {
    ptr = kbuf + ((long)t * NKV_SZ + (h - NH_SZ)) * 256;
    w = kw;
  }
  float x = ptr[d];
  float s2 = x * x;
#pragma unroll
  for (int o = 32; o > 0; o >>= 1) s2 += __shfl_down(s2, o);
  if ((d & 63) == 0) red[d >> 6] = s2;
  __syncthreads();
  float tot = red[0] + red[1] + red[2] + red[3];
  float sc = rsqrtf(tot * (1.0f / 256.0f) + EPS_);
  buf[d] = x * sc * (1.0f + w[d]);
  __syncthreads();
  float outv;
  if (d < 64) {
    int i = d & 31;
    float p = (float)pos[(i % 3) * T_SZ + t];
    float fr = p * exp2f((float)i * (-0.72667177075661f));  // 1e7^(-i/32)
    float c, s;
    sincosf(fr, &s, &c);
    if (d < 32)
      outv = buf[d] * c - buf[d + 32] * s;
    else
      outv = buf[d] * c + buf[d - 32] * s;
  } else {
    outv = buf[d];
  }
  ((unsigned*)ptr)[d] = pack_hilo(outv);
}

// ------------------------------------------------------- flash causal attention
// Q: packed hi/lo (T,16,256); K: packed hi/lo (T,2,256); VT bf16 (2,256,T);
// gate bf16 (T,16,256); output packed hi/lo written IN-PLACE over Q buffer.
__global__ __launch_bounds__(256) void attn_kernel(unsigned* __restrict__ Qp,
                                                   const unsigned* __restrict__ Kp,
                                                   const __hip_bfloat16* __restrict__ VT,
                                                   const __hip_bfloat16* __restrict__ Gt,
                                                   int nkt_unused) {
  const int qt = blockIdx.x, h = blockIdx.y, kvh = h >> 3;
  const int tid = threadIdx.x, wid = tid >> 6, lane = tid & 63;
  const int lo = lane & 15, quad = lane >> 4;
  __shared__ __align__(16) __hip_bfloat16 KVs[64 * 256];  // K_hi tile OR V^T tile
  __shared__ __align__(16) __hip_bfloat16 Ps[4][16 * 64];

  // Q fragments hi+lo (A-layout): row = lane&15 (of wave's 16), k = quad*8 + kc*32 + j
  bf16x8 qh[8], ql[8];
  {
    const unsigned* qp =
        Qp + ((long)(qt * 64 + wid * 16 + lo) * NH_SZ + h) * 256 + quad * 8;
#pragma unroll
    for (int kc = 0; kc < 8; ++kc) {
      uint4 p0 = *(const uint4*)(qp + kc * 32);
      uint4 p1 = *(const uint4*)(qp + kc * 32 + 4);
      bf16x8 a, b;
      a[0] = (short)(p0.x & 0xffff); b[0] = (short)(p0.x >> 16);
      a[1] = (short)(p0.y & 0xffff); b[1] = (short)(p0.y >> 16);
      a[2] = (short)(p0.z & 0xffff); b[2] = (short)(p0.z >> 16);
      a[3] = (short)(p0.w & 0xffff); b[3] = (short)(p0.w >> 16);
      a[4] = (short)(p1.x & 0xffff); b[4] = (short)(p1.x >> 16);
      a[5] = (short)(p1.y & 0xffff); b[5] = (short)(p1.y >> 16);
      a[6] = (short)(p1.z & 0xffff); b[6] = (short)(p1.z >> 16);
      a[7] = (short)(p1.w & 0xffff); b[7] = (short)(p1.w >> 16);
      qh[kc] = a; ql[kc] = b;
    }
  }

  const f32x4 z4 = {0.f, 0.f, 0.f, 0.f};
  f32x4 acc[16];
#pragma unroll
  for (int od = 0; od < 16; ++od) acc[od] = z4;
  float m_r[4], l_r[4];
#pragma unroll
  for (int r = 0; r < 4; ++r) { m_r[r] = -1e30f; l_r[r] = 0.f; }

  const int qrow_g = qt * 64 + wid * 16 + quad * 4;

  for (int kt = 0; kt <= qt; ++kt) {
    // stage K_hi tile [64 kv][256 hd] from packed (VGPR unpack -> ds_write 8B)
#pragma unroll
    for (int it = 0; it < 16; ++it) {
      int cf = it * 256 + tid, row = cf >> 6, c4 = (cf & 63) * 4;
      uint4 p = *(const uint4*)(Kp + ((long)(kt * 64 + row) * NKV_SZ + kvh) * 256 + c4);
      uint2 w2;
      w2.x = (p.x & 0xffff) | ((p.y & 0xffff) << 16);
      w2.y = (p.z & 0xffff) | ((p.w & 0xffff) << 16);
      *(uint2*)(KVs + row * 256 + c4) = w2;
    }
    __syncthreads();
    // scores: 2-pass (Q_hi + Q_lo) x K_hi
    f32x4 s[4];
#pragma unroll
    for (int ni = 0; ni < 4; ++ni) s[ni] = z4;
#pragma unroll
    for (int kc = 0; kc < 8; ++kc) {
      bf16x8 ah = qh[kc], al = ql[kc];
#pragma unroll
      for (int ni = 0; ni < 4; ++ni) {
        bf16x8 b = *(const bf16x8*)(KVs + (ni * 16 + lo) * 256 + kc * 32 + quad * 8);
        s[ni] = MFMA16(ah, b, s[ni]);
        s[ni] = MFMA16(al, b, s[ni]);
      }
    }
    __syncthreads();  // K reads done
    // stage V^T tile [256 hd][64 kv] (async; overlaps softmax VALU)
#pragma unroll
    for (int it = 0; it < 8; ++it) {
      int cf = it * 256 + tid, row = cf >> 3, col = (cf & 7) * 8;
      async16(VT + ((long)(kvh * 256 + row)) * T_SZ + kt * 64 + col, KVs + cf * 8);
    }
    // online softmax
    float sv[4][4];
#pragma unroll
    for (int ni = 0; ni < 4; ++ni) {
      int kcol = kt * 64 + ni * 16 + lo;
#pragma unroll
      for (int r = 0; r < 4; ++r) {
        float v = s[ni][r] * ATT_SCALE;
        sv[ni][r] = (kcol > qrow_g + r) ? -1e30f : v;
      }
    }
#pragma unroll
    for (int r = 0; r < 4; ++r) {
      float mx = fmaxf(fmaxf(sv[0][r], sv[1][r]), fmaxf(sv[2][r], sv[3][r]));
#pragma unroll
      for (int off = 1; off < 16; off <<= 1) mx = fmaxf(mx, __shfl_xor(mx, off));
      float mnew = fmaxf(m_r[r], mx);
      float alpha = __expf(m_r[r] - mnew);
      float su = 0.f;
#pragma unroll
      for (int ni = 0; ni < 4; ++ni) {
        float e = __expf(sv[ni][r] - mnew);
        sv[ni][r] = e;
        su += e;
      }
#pragma unroll
      for (int off = 1; off < 16; off <<= 1) su += __shfl_xor(su, off);
      l_r[r] = l_r[r] * alpha + su;
      m_r[r] = mnew;
#pragma unroll
      for (int od = 0; od < 16; ++od) acc[od][r] *= alpha;
    }
#pragma unroll
    for (int ni = 0; ni < 4; ++ni)
#pragma unroll
      for (int r = 0; r < 4; ++r)
        Ps[wid][(quad * 4 + r) * 64 + ni * 16 + lo] = __float2bfloat16(sv[ni][r]);
    __syncthreads();  // V^T ready
#pragma unroll
    for (int kc2 = 0; kc2 < 2; ++kc2) {
      bf16x8 ap = *(const bf16x8*)(&Ps[wid][lo * 64 + kc2 * 32 + quad * 8]);
#pragma unroll
      for (int od = 0; od < 16; ++od) {
        bf16x8 bv = *(const bf16x8*)(KVs + (od * 16 + lo) * 64 + kc2 * 32 + quad * 8);
        acc[od] = MFMA16(ap, bv, acc[od]);
      }
    }
    __syncthreads();  // V reads done before next K staging
  }

  // epilogue: O /= l, * sigmoid(gate) fp32, write packed hi/lo in-place over Q
#pragma unroll
  for (int od = 0; od < 16; ++od)
#pragma unroll
    for (int r = 0; r < 4; ++r) {
      int trow = qt * 64 + wid * 16 + quad * 4 + r;
      int col = od * 16 + lo;
      long idx = ((long)trow * NH_SZ + h) * 256 + col;
      float g = __bfloat162float(Gt[idx]);
      float sig = 1.0f / (1.0f + expf(-g));
      float v = (acc[od][r] / l_r[r]) * sig;
      Qp[idx] = pack_hilo(v);
    }
}

// ------------------------------- out GEMM: A packed hi/lo, B hi/lo, 3-pass, fp32 out
__global__ __launch_bounds__(256) void gemm_out(const unsigned* __restrict__ Ap,
                                                const __hip_bfloat16* __restrict__ Bh,
                                                const __hip_bfloat16* __restrict__ Bl,
                                                float* __restrict__ C,
                                                int M, int N, int K) {
  __shared__ __align__(16) __hip_bfloat16 Ash[128 * 32];
  __shared__ __align__(16) __hip_bfloat16 Asl[128 * 32];
  __shared__ __align__(16) __hip_bfloat16 Bsh[128 * 32];
  __shared__ __align__(16) __hip_bfloat16 Bsl[128 * 32];
  const int tid = threadIdx.x;
  const int wid = tid >> 6, lane = tid & 63;
  const int lo = lane & 15, quad = lane >> 4;
  const long m0 = (long)blockIdx.y * 128, n0 = (long)blockIdx.x * 128;
  const int wm = (wid >> 1) * 64, wn = (wid & 1) * 64;
  const f32x4 z4 = {0.f, 0.f, 0.f, 0.f};
  f32x4 acc[4][4];
#pragma unroll
  for (int i = 0; i < 4; ++i)
#pragma unroll
    for (int j = 0; j < 4; ++j) acc[i][j] = z4;

  const int cf0 = tid, cf1 = 256 + tid;
  const int br0 = cf0 >> 2, bc0 = (cf0 & 3) * 8;
  const int br1 = cf1 >> 2, bc1 = (cf1 & 3) * 8;
  const __hip_bfloat16* bh0 = Bh + (n0 + br0) * K + bc0;
  const __hip_bfloat16* bh1 = Bh + (n0 + br1) * K + bc1;
  const __hip_bfloat16* bl0 = Bl + (n0 + br0) * K + bc0;
  const __hip_bfloat16* bl1 = Bl + (n0 + br1) * K + bc1;

  for (int k0 = 0; k0 < K; k0 += 32) {
    async16(bh0 + k0, Bsh + cf0 * 8);
    async16(bh1 + k0, Bsh + cf1 * 8);
    async16(bl0 + k0, Bsl + cf0 * 8);
    async16(bl1 + k0, Bsl + cf1 * 8);
    // A staging: unpack packed hi/lo (128x32 uint = 1024 uint4 chunks, 4 iters)
#pragma unroll
    for (int it = 0; it < 4; ++it) {
      int c = it * 256 + tid, row = c >> 3, c4 = (c & 7) * 4;
      uint4 p = *(const uint4*)(Ap + (m0 + row) * K + k0 + c4);
      uint2 wh, wl;
      wh.x = (p.x & 0xffff) | ((p.y & 0xffff) << 16);
      wh.y = (p.z & 0xffff) | ((p.w & 0xffff) << 16);
      wl.x = (p.x >> 16) | (p.y & 0xffff0000u);
      wl.y = (p.z >> 16) | (p.w & 0xffff0000u);
      *(uint2*)(Ash + row * 32 + c4) = wh;
      *(uint2*)(Asl + row * 32 + c4) = wl;
    }
    __syncthreads();
    bf16x8 ah[4], al[4], bh[4], bl[4];
#pragma unroll
    for (int i = 0; i < 4; ++i) {
      ah[i] = *(const bf16x8*)(Ash + (wm + i * 16 + lo) * 32 + quad * 8);
      al[i] = *(const bf16x8*)(Asl + (wm + i * 16 + lo) * 32 + quad * 8);
      bh[i] = *(const bf16x8*)(Bsh + (wn + i * 16 + lo) * 32 + quad * 8);
      bl[i] = *(const bf16x8*)(Bsl + (wn + i * 16 + lo) * 32 + quad * 8);
    }
#pragma unroll
    for (int i = 0; i < 4; ++i)
#pragma unroll
      for (int j = 0; j < 4; ++j) {
        acc[i][j] = MFMA16(ah[i], bh[j], acc[i][j]);
        acc[i][j] = MFMA16(al[i], bh[j], acc[i][j]);
        acc[i][j] = MFMA16(ah[i], bl[j], acc[i][j]);
      }
    __syncthreads();
  }
#pragma unroll
  for (int i = 0; i < 4; ++i)
#pragma unroll
    for (int j = 0; j < 4; ++j)
#pragma unroll
      for (int r = 0; r < 4; ++r) {
        long row = m0 + wm + i * 16 + quad * 4 + r;
        long col = n0 + wn + j * 16 + lo;
        C[row * N + col] = acc[i][j][r];
      }
}

// ------------------------------------------------------------------- launcher
extern "C" void kernel_launch(void* const* d_in, const int* in_sizes, int n_in,
                              void* d_out, int out_size, void* d_ws, size_t ws_size,
                              hipStream_t stream) {
  (void)in_sizes; (void)n_in; (void)out_size; (void)ws_size;
  const int* positions = (const int*)d_in[0];
  const float* hidden = (const float*)d_in[1];
  const float* Wq = (const float*)d_in[2];
  const float* Wk = (const float*)d_in[3];
  const float* Wv = (const float*)d_in[4];
  const float* Wo = (const float*)d_in[5];
  const float* qw = (const float*)d_in[6];
  const float* kw = (const float*)d_in[7];
  float* out = (float*)d_out;
  char* ws = (char*)d_ws;

  // layout (bytes), total exactly 160 MiB:
  __hip_bfloat16* hid  = (__hip_bfloat16*)(ws + 0);           // 16 MB
  __hip_bfloat16* WqT  = (__hip_bfloat16*)(ws + 16777216);    // 32 MB
  __hip_bfloat16* WkT  = (__hip_bfloat16*)(ws + 50331648);    //  2 MB
  __hip_bfloat16* WvT  = (__hip_bfloat16*)(ws + 52428800);    //  2 MB
  float*          qf   = (float*)(ws + 54525952);             // 64 MB (T,16,256) fp32 -> packed -> o packed
  __hip_bfloat16* gate = (__hip_bfloat16*)(ws + 121634816);   // 32 MB (T,16,256)
  float*          kf   = (float*)(ws + 155189248);            //  8 MB (T,2,256) fp32 -> packed
  __hip_bfloat16* vraw = (__hip_bfloat16*)(ws + 163577856);   //  4 MB -> end 167,772,160
  __hip_bfloat16* vT   = WkT;                                  // alias [48,52) after k/v GEMMs
  __hip_bfloat16* WoTh = gate;                                 // alias gate region after attn
  __hip_bfloat16* WoTl = (__hip_bfloat16*)(ws + 138412032);    // gate region second half
  unsigned* qpk = (unsigned*)qf;
  unsigned* kpk = (unsigned*)kf;

  // 1) casts / transposes
  cast_f32_bf16<<<dim3(8192), dim3(256), 0, stream>>>(hidden, hid, 2097152);
  transpose_cast<float><<<dim3(256, 64), dim3(256), 0, stream>>>(Wq, WqT, 2048, 8192);
  transpose_cast<float><<<dim3(16, 64), dim3(256), 0, stream>>>(Wk, WkT, 2048, 512);
  transpose_cast<float><<<dim3(16, 64), dim3(256), 0, stream>>>(Wv, WvT, 2048, 512);
  // 2) projections: q fp32 + gate bf16; k fp32; v bf16
  gemm_qg<<<dim3(64, 32), dim3(256), 0, stream>>>(hid, WqT, qf, gate, 4096, 8192, 2048);
  gemm_bt<1><<<dim3(4, 32), dim3(256), 0, stream>>>(hid, WkT, kf, 4096, 512, 2048);
  gemm_bt<0><<<dim3(4, 32), dim3(256), 0, stream>>>(hid, WvT, vraw, 4096, 512, 2048);
  // 3) V -> V^T (2,256,T), bf16
  transpose_cast<__hip_bfloat16><<<dim3(16, 128), dim3(256), 0, stream>>>(vraw, vT, 4096, 512);
  // 4) RMSNorm + RoPE (fp32), pack hi/lo in-place
  norm_rope_pack<<<dim3(4096, 18), dim3(256), 0, stream>>>(qf, kf, positions, qw, kw);
  // 5) flash attention; writes o packed hi/lo in-place over q buffer
  attn_kernel<<<dim3(64, 16), dim3(256), 0, stream>>>(qpk, kpk, vT, gate, 0);
  // 6) Wo -> hi/lo transpose (into dead gate region), then 3-pass out GEMM
  transpose_split<<<dim3(64, 128), dim3(256), 0, stream>>>(Wo, WoTh, WoTl, 4096, 2048);
  gemm_out<<<dim3(16, 32), dim3(256), 0, stream>>>(qpk, WoTh, WoTl, out, 4096, 2048, 4096);
}

// Round 4
// 1435.885 us; speedup vs baseline: 1.2865x; 1.2865x over previous
//
#include <hip/hip_runtime.h>
#include <hip/hip_bf16.h>

// Qwen3.5 attention block: T=4096, H=2048, NH=16, NKV=2, HD=256, ROT=64
// bf16 MFMA (16x16x32) with fp32 accumulate; precision-critical intermediates
// kept fp32 or split into bf16 hi/lo pairs (packed ushort2 in 4B slots).

#define T_SZ 4096
#define H_SZ 2048
#define NH_SZ 16
#define NKV_SZ 2
#define HD_SZ 256
#define ATT_SCALE 0.0625f   // HD^-0.5
#define EPS_ 1e-6f

typedef __attribute__((ext_vector_type(8))) short bf16x8;   // 8 bf16 = 4 VGPRs
typedef __attribute__((ext_vector_type(4))) float f32x4;

#define MFMA16(a, b, c) __builtin_amdgcn_mfma_f32_16x16x32_bf16((a), (b), (c), 0, 0, 0)

__device__ __forceinline__ void async16(const void* g, void* l) {
  __builtin_amdgcn_global_load_lds((const __attribute__((address_space(1))) void*)g,
                                   (__attribute__((address_space(3))) void*)l,
                                   16, 0, 0);
}

__device__ __forceinline__ float to_f(float x) { return x; }
__device__ __forceinline__ float to_f(__hip_bfloat16 x) { return __bfloat162float(x); }

union BfBits { __hip_bfloat16 h; unsigned short u; };

__device__ __forceinline__ unsigned short bf16_bits(__hip_bfloat16 h) {
  BfBits t; t.h = h; return t.u;
}

__device__ __forceinline__ unsigned pack_hilo(float v) {
  __hip_bfloat16 hi = __float2bfloat16(v);
  float rem = v - __bfloat162float(hi);
  __hip_bfloat16 lo = __float2bfloat16(rem);
  return (unsigned)bf16_bits(hi) | ((unsigned)bf16_bits(lo) << 16);
}

// ---------------------------------------------------------------- cast hidden
__global__ __launch_bounds__(256) void cast_f32_bf16(const float* __restrict__ in,
                                                     __hip_bfloat16* __restrict__ out,
                                                     int n4) {
  int i = blockIdx.x * 256 + threadIdx.x;
  if (i >= n4) return;
  float4 v = ((const float4*)in)[i];
  union { __hip_bfloat16 h[4]; uint2 u; } t;
  t.h[0] = __float2bfloat16(v.x);
  t.h[1] = __float2bfloat16(v.y);
  t.h[2] = __float2bfloat16(v.z);
  t.h[3] = __float2bfloat16(v.w);
  ((uint2*)out)[i] = t.u;
}

// ------------------------------------------------------- transpose (+cast bf16)
template <typename TIN>
__global__ __launch_bounds__(256) void transpose_cast(const TIN* __restrict__ in,
                                                      __hip_bfloat16* __restrict__ out,
                                                      int R, int C) {
  __shared__ TIN tile[32][33];
  int c0 = blockIdx.x * 32, r0 = blockIdx.y * 32;
  int tx = threadIdx.x & 31, ty = threadIdx.x >> 5;
#pragma unroll
  for (int i = 0; i < 32; i += 8)
    tile[ty + i][tx] = in[(long)(r0 + ty + i) * C + c0 + tx];
  __syncthreads();
#pragma unroll
  for (int i = 0; i < 32; i += 8)
    out[(long)(c0 + ty + i) * R + r0 + tx] = __float2bfloat16(to_f(tile[tx][ty + i]));
}

// transpose fp32 -> bf16 hi + bf16 lo (for Wo split)
__global__ __launch_bounds__(256) void transpose_split(const float* __restrict__ in,
                                                       __hip_bfloat16* __restrict__ oh,
                                                       __hip_bfloat16* __restrict__ ol,
                                                       int R, int C) {
  __shared__ float tile[32][33];
  int c0 = blockIdx.x * 32, r0 = blockIdx.y * 32;
  int tx = threadIdx.x & 31, ty = threadIdx.x >> 5;
#pragma unroll
  for (int i = 0; i < 32; i += 8)
    tile[ty + i][tx] = in[(long)(r0 + ty + i) * C + c0 + tx];
  __syncthreads();
#pragma unroll
  for (int i = 0; i < 32; i += 8) {
    float v = tile[tx][ty + i];
    __hip_bfloat16 hi = __float2bfloat16(v);
    __hip_bfloat16 lo = __float2bfloat16(v - __bfloat162float(hi));
    long idx = (long)(c0 + ty + i) * R + r0 + tx;
    oh[idx] = hi;
    ol[idx] = lo;
  }
}

// ------------------------------------------------------------------ GEMM (B^T)
template <int OUTF32>
__global__ __launch_bounds__(256) void gemm_bt(const __hip_bfloat16* __restrict__ A,
                                               const __hip_bfloat16* __restrict__ BT,
                                               void* __restrict__ Cp,
                                               int M, int N, int K) {
  __shared__ __align__(16) __hip_bfloat16 As[128 * 32];
  __shared__ __align__(16) __hip_bfloat16 Bs[128 * 32];
  const int tid = threadIdx.x;
  const int wid = tid >> 6, lane = tid & 63;
  const int lo = lane & 15, quad = lane >> 4;
  const long m0 = (long)blockIdx.y * 128, n0 = (long)blockIdx.x * 128;
  const int wm = (wid >> 1) * 64, wn = (wid & 1) * 64;
  const f32x4 z4 = {0.f, 0.f, 0.f, 0.f};
  f32x4 acc[4][4];
#pragma unroll
  for (int i = 0; i < 4; ++i)
#pragma unroll
    for (int j = 0; j < 4; ++j) acc[i][j] = z4;

  const int cf0 = tid, cf1 = 256 + tid;
  const int r0_ = cf0 >> 2, c0_ = (cf0 & 3) * 8;
  const int r1_ = cf1 >> 2, c1_ = (cf1 & 3) * 8;
  const __hip_bfloat16* a0 = A + (m0 + r0_) * K + c0_;
  const __hip_bfloat16* a1 = A + (m0 + r1_) * K + c1_;
  const __hip_bfloat16* b0 = BT + (n0 + r0_) * K + c0_;
  const __hip_bfloat16* b1 = BT + (n0 + r1_) * K + c1_;

  for (int k0 = 0; k0 < K; k0 += 32) {
    async16(a0 + k0, As + cf0 * 8);
    async16(a1 + k0, As + cf1 * 8);
    async16(b0 + k0, Bs + cf0 * 8);
    async16(b1 + k0, Bs + cf1 * 8);
    __syncthreads();
    bf16x8 af[4], bfv[4];
#pragma unroll
    for (int i = 0; i < 4; ++i)
      af[i] = *(const bf16x8*)(As + (wm + i * 16 + lo) * 32 + quad * 8);
#pragma unroll
    for (int i = 0; i < 4; ++i)
      bfv[i] = *(const bf16x8*)(Bs + (wn + i * 16 + lo) * 32 + quad * 8);
#pragma unroll
    for (int i = 0; i < 4; ++i)
#pragma unroll
      for (int j = 0; j < 4; ++j) acc[i][j] = MFMA16(af[i], bfv[j], acc[i][j]);
    __syncthreads();
  }
#pragma unroll
  for (int i = 0; i < 4; ++i)
#pragma unroll
    for (int j = 0; j < 4; ++j)
#pragma unroll
      for (int r = 0; r < 4; ++r) {
        long row = m0 + wm + i * 16 + quad * 4 + r;
        long col = n0 + wn + j * 16 + lo;
        float v = acc[i][j][r];
        if (OUTF32)
          ((float*)Cp)[row * N + col] = v;
        else
          ((__hip_bfloat16*)Cp)[row * N + col] = __float2bfloat16(v);
      }
}

// ------------------------------------------- Wq GEMM with q(fp32)/gate(bf16) split
__global__ __launch_bounds__(256) void gemm_qg(const __hip_bfloat16* __restrict__ A,
                                               const __hip_bfloat16* __restrict__ BT,
                                               float* __restrict__ qout,
                                               __hip_bfloat16* __restrict__ gate,
                                               int M, int N, int K) {
  __shared__ __align__(16) __hip_bfloat16 As[128 * 32];
  __shared__ __align__(16) __hip_bfloat16 Bs[128 * 32];
  const int tid = threadIdx.x;
  const int wid = tid >> 6, lane = tid & 63;
  const int lo = lane & 15, quad = lane >> 4;
  const long m0 = (long)blockIdx.y * 128, n0 = (long)blockIdx.x * 128;
  const int wm = (wid >> 1) * 64, wn = (wid & 1) * 64;
  const f32x4 z4 = {0.f, 0.f, 0.f, 0.f};
  f32x4 acc[4][4];
#pragma unroll
  for (int i = 0; i < 4; ++i)
#pragma unroll
    for (int j = 0; j < 4; ++j) acc[i][j] = z4;

  const int cf0 = tid, cf1 = 256 + tid;
  const int r0_ = cf0 >> 2, c0_ = (cf0 & 3) * 8;
  const int r1_ = cf1 >> 2, c1_ = (cf1 & 3) * 8;
  const __hip_bfloat16* a0 = A + (m0 + r0_) * K + c0_;
  const __hip_bfloat16* a1 = A + (m0 + r1_) * K + c1_;
  const __hip_bfloat16* b0 = BT + (n0 + r0_) * K + c0_;
  const __hip_bfloat16* b1 = BT + (n0 + r1_) * K + c1_;

  for (int k0 = 0; k0 < K; k0 += 32) {
    async16(a0 + k0, As + cf0 * 8);
    async16(a1 + k0, As + cf1 * 8);
    async16(b0 + k0, Bs + cf0 * 8);
    async16(b1 + k0, Bs + cf1 * 8);
    __syncthreads();
    bf16x8 af[4], bfv[4];
#pragma unroll
    for (int i = 0; i < 4; ++i)
      af[i] = *(const bf16x8*)(As + (wm + i * 16 + lo) * 32 + quad * 8);
#pragma unroll
    for (int i = 0; i < 4; ++i)
      bfv[i] = *(const bf16x8*)(Bs + (wn + i * 16 + lo) * 32 + quad * 8);
#pragma unroll
    for (int i = 0; i < 4; ++i)
#pragma unroll
      for (int j = 0; j < 4; ++j) acc[i][j] = MFMA16(af[i], bfv[j], acc[i][j]);
    __syncthreads();
  }
#pragma unroll
  for (int i = 0; i < 4; ++i)
#pragma unroll
    for (int j = 0; j < 4; ++j)
#pragma unroll
      for (int r = 0; r < 4; ++r) {
        long row = m0 + wm + i * 16 + quad * 4 + r;  // token t
        long col = n0 + wn + j * 16 + lo;            // n in [0,8192)
        int head = (int)(col >> 9), c = (int)(col & 511);
        float v = acc[i][j][r];
        if (c < 256)
          qout[(row * NH_SZ + head) * 256 + c] = v;
        else
          gate[(row * NH_SZ + head) * 256 + (c - 256)] = __float2bfloat16(v);
      }
}

// ------------------- RMSNorm + RoPE from fp32; q: packed hi/lo in-place, k: bf16
__global__ __launch_bounds__(256) void norm_rope_pack(float* __restrict__ qbuf,
                                                      const float* __restrict__ kbuf,
                                                      __hip_bfloat16* __restrict__ kn,
                                                      const int* __restrict__ pos,
                                                      const float* __restrict__ qw,
                                                      const float* __restrict__ kw) {
  const int t = blockIdx.x, h = blockIdx.y, d = threadIdx.x;
  __shared__ float buf[256];
  __shared__ float red[4];
  const float* ptr;
  const float* w;
  if (h < NH_SZ) {
    ptr = qbuf + ((long)t * NH_SZ + h) * 256;
    w = qw;
  } else {
    ptr = kbuf + ((long)t * NKV_SZ + (h - NH_SZ)) * 256;
    w = kw;
  }
  float x = ptr[d];
  float s2 = x * x;
#pragma unroll
  for (int o = 32; o > 0; o >>= 1) s2 += __shfl_down(s2, o);
  if ((d & 63) == 0) red[d >> 6] = s2;
  __syncthreads();
  float tot = red[0] + red[1] + red[2] + red[3];
  float sc = rsqrtf(tot * (1.0f / 256.0f) + EPS_);
  buf[d] = x * sc * (1.0f + w[d]);
  __syncthreads();
  float outv;
  if (d < 64) {
    int i = d & 31;
    float p = (float)pos[(i % 3) * T_SZ + t];
    float fr = p * exp2f((float)i * (-0.72667177075661f));  // 1e7^(-i/32)
    float c, s;
    sincosf(fr, &s, &c);
    if (d < 32)
      outv = buf[d] * c - buf[d + 32] * s;
    else
      outv = buf[d] * c + buf[d - 32] * s;
  } else {
    outv = buf[d];
  }
  if (h < NH_SZ)
    ((unsigned*)qbuf)[((long)t * NH_SZ + h) * 256 + d] = pack_hilo(outv);
  else
    kn[((long)t * NKV_SZ + (h - NH_SZ)) * 256 + d] = __float2bfloat16(outv);
}

// ------------------------------------------------------- flash causal attention
// Q packed hi/lo (T,16,256); K bf16 (T,2,256); VT bf16 (2,256,T); gate bf16.
// Output packed hi/lo written IN-PLACE over Q buffer.
// Grid (32,16): block p handles q-tiles p and 63-p (balanced: 65 iters each).
// LDS: chunked layouts -> conflict-free MFMA fragment reads; async16 staging.
__global__ __launch_bounds__(256) void attn_kernel(unsigned* __restrict__ Qp,
                                                   const __hip_bfloat16* __restrict__ KN,
                                                   const __hip_bfloat16* __restrict__ VT,
                                                   const __hip_bfloat16* __restrict__ Gt) {
  const int p = blockIdx.x, h = blockIdx.y, kvh = h >> 3;
  const int tid = threadIdx.x, wid = tid >> 6, lane = tid & 63;
  const int lo = lane & 15, quad = lane >> 4;
  __shared__ __align__(16) __hip_bfloat16 Ks[32 * 512];   // [chunk=hd/8][kv=64][8]
  __shared__ __align__(16) __hip_bfloat16 Vs[8 * 2048];   // [chunk=kv/8][hd=256][8]
  __shared__ __align__(16) __hip_bfloat16 Ps[4][16 * 72]; // per-wave, stride 72

  __hip_bfloat16* myP = &Ps[wid][0];
  const f32x4 z4 = {0.f, 0.f, 0.f, 0.f};

  for (int side = 0; side < 2; ++side) {
    const int qt = side ? 63 - p : p;

    // Q fragments hi+lo (A-layout): row = lane&15, k = quad*8 + kc*32 + j
    bf16x8 qh[8], ql[8];
    {
      const unsigned* qp =
          Qp + ((long)(qt * 64 + wid * 16 + lo) * NH_SZ + h) * 256 + quad * 8;
#pragma unroll
      for (int kc = 0; kc < 8; ++kc) {
        uint4 p0 = *(const uint4*)(qp + kc * 32);
        uint4 p1 = *(const uint4*)(qp + kc * 32 + 4);
        bf16x8 a, b;
        a[0] = (short)(p0.x & 0xffff); b[0] = (short)(p0.x >> 16);
        a[1] = (short)(p0.y & 0xffff); b[1] = (short)(p0.y >> 16);
        a[2] = (short)(p0.z & 0xffff); b[2] = (short)(p0.z >> 16);
        a[3] = (short)(p0.w & 0xffff); b[3] = (short)(p0.w >> 16);
        a[4] = (short)(p1.x & 0xffff); b[4] = (short)(p1.x >> 16);
        a[5] = (short)(p1.y & 0xffff); b[5] = (short)(p1.y >> 16);
        a[6] = (short)(p1.z & 0xffff); b[6] = (short)(p1.z >> 16);
        a[7] = (short)(p1.w & 0xffff); b[7] = (short)(p1.w >> 16);
        qh[kc] = a; ql[kc] = b;
      }
    }

    f32x4 acc[16];
#pragma unroll
    for (int od = 0; od < 16; ++od) acc[od] = z4;
    float m_r[4], l_r[4];
#pragma unroll
    for (int r = 0; r < 4; ++r) { m_r[r] = -1e30f; l_r[r] = 0.f; }

    const int qrow_g = qt * 64 + wid * 16 + quad * 4;

    // stage K(0), V(0): chunk-column async16 (LDS = uniform + lane*16)
#pragma unroll
    for (int j = 0; j < 8; ++j) {
      int c = j * 4 + wid;
      async16(KN + ((long)(0 * 64 + lane) * NKV_SZ + kvh) * 256 + c * 8,
              Ks + c * 512 + lane * 8);
    }
#pragma unroll
    for (int j = 0; j < 8; ++j) {
      int idx = j * 4 + wid, c = idx >> 2, g = idx & 3;
      int row = g * 64 + lane;
      async16(VT + ((long)kvh * 256 + row) * T_SZ + 0 * 64 + c * 8,
              Vs + c * 2048 + row * 8);
    }

    for (int kt = 0; kt <= qt; ++kt) {
      __syncthreads();  // staging of K(kt),V(kt) drained; prev-iter reads done
      // scores: 2-pass (Q_hi + Q_lo) x K
      f32x4 s[4];
#pragma unroll
      for (int ni = 0; ni < 4; ++ni) s[ni] = z4;
#pragma unroll
      for (int kc = 0; kc < 8; ++kc) {
        bf16x8 ah = qh[kc], al = ql[kc];
#pragma unroll
        for (int ni = 0; ni < 4; ++ni) {
          bf16x8 b = *(const bf16x8*)(Ks + (kc * 4 + quad) * 512 + (ni * 16 + lo) * 8);
          s[ni] = MFMA16(ah, b, s[ni]);
          s[ni] = MFMA16(al, b, s[ni]);
        }
      }
      // online softmax (VALU only)
      float sv[4][4];
#pragma unroll
      for (int ni = 0; ni < 4; ++ni) {
        int kcol = kt * 64 + ni * 16 + lo;
#pragma unroll
        for (int r = 0; r < 4; ++r) {
          float v = s[ni][r] * ATT_SCALE;
          sv[ni][r] = (kcol > qrow_g + r) ? -1e30f : v;
        }
      }
#pragma unroll
      for (int r = 0; r < 4; ++r) {
        float mx = fmaxf(fmaxf(sv[0][r], sv[1][r]), fmaxf(sv[2][r], sv[3][r]));
#pragma unroll
        for (int off = 1; off < 16; off <<= 1) mx = fmaxf(mx, __shfl_xor(mx, off));
        float mnew = fmaxf(m_r[r], mx);
        float alpha = __expf(m_r[r] - mnew);
        float su = 0.f;
#pragma unroll
        for (int ni = 0; ni < 4; ++ni) {
          float e = __expf(sv[ni][r] - mnew);
          sv[ni][r] = e;
          su += e;
        }
#pragma unroll
        for (int off = 1; off < 16; off <<= 1) su += __shfl_xor(su, off);
        l_r[r] = l_r[r] * alpha + su;
        m_r[r] = mnew;
#pragma unroll
        for (int od = 0; od < 16; ++od) acc[od][r] *= alpha;
      }
      // write P to own-wave LDS (no barrier needed: per-wave buffer)
#pragma unroll
      for (int ni = 0; ni < 4; ++ni)
#pragma unroll
        for (int r = 0; r < 4; ++r)
          myP[(quad * 4 + r) * 72 + ni * 16 + lo] = __float2bfloat16(sv[ni][r]);
      // O += P V  (V(kt) arrived at this iter's top barrier)
#pragma unroll
      for (int kc2 = 0; kc2 < 2; ++kc2) {
        bf16x8 ap = *(const bf16x8*)(myP + lo * 72 + kc2 * 32 + quad * 8);
#pragma unroll
        for (int od = 0; od < 16; ++od) {
          bf16x8 bv = *(const bf16x8*)(Vs + (kc2 * 4 + quad) * 2048 + (od * 16 + lo) * 8);
          acc[od] = MFMA16(ap, bv, acc[od]);
        }
      }
      __syncthreads();  // all waves done reading Ks/Vs
      if (kt < qt) {
        int ktn = kt + 1;
#pragma unroll
        for (int j = 0; j < 8; ++j) {
          int c = j * 4 + wid;
          async16(KN + ((long)(ktn * 64 + lane) * NKV_SZ + kvh) * 256 + c * 8,
                  Ks + c * 512 + lane * 8);
        }
#pragma unroll
        for (int j = 0; j < 8; ++j) {
          int idx = j * 4 + wid, c = idx >> 2, g = idx & 3;
          int row = g * 64 + lane;
          async16(VT + ((long)kvh * 256 + row) * T_SZ + ktn * 64 + c * 8,
                  Vs + c * 2048 + row * 8);
        }
      }
    }

    // epilogue: O /= l, * sigmoid(gate) fp32, write packed hi/lo in-place over Q
#pragma unroll
    for (int od = 0; od < 16; ++od)
#pragma unroll
      for (int r = 0; r < 4; ++r) {
        int trow = qt * 64 + wid * 16 + quad * 4 + r;
        int col = od * 16 + lo;
        long idx = ((long)trow * NH_SZ + h) * 256 + col;
        float g = __bfloat162float(Gt[idx]);
        float sig = 1.0f / (1.0f + expf(-g));
        float v = (acc[od][r] / l_r[r]) * sig;
        Qp[idx] = pack_hilo(v);
      }
  }
}

// ------------------------------- out GEMM: A packed hi/lo, B hi/lo, 3-pass, fp32 out
__global__ __launch_bounds__(256) void gemm_out(const unsigned* __restrict__ Ap,
                                                const __hip_bfloat16* __restrict__ Bh,
                                                const __hip_bfloat16* __restrict__ Bl,
                                                float* __restrict__ C,
                                                int M, int N, int K) {
  __shared__ __align__(16) __hip_bfloat16 Ash[128 * 32];
  __shared__ __align__(16) __hip_bfloat16 Asl[128 * 32];
  __shared__ __align__(16) __hip_bfloat16 Bsh[128 * 32];
  __shared__ __align__(16) __hip_bfloat16 Bsl[128 * 32];
  const int tid = threadIdx.x;
  const int wid = tid >> 6, lane = tid & 63;
  const int lo = lane & 15, quad = lane >> 4;
  const long m0 = (long)blockIdx.y * 128, n0 = (long)blockIdx.x * 128;
  const int wm = (wid >> 1) * 64, wn = (wid & 1) * 64;
  const f32x4 z4 = {0.f, 0.f, 0.f, 0.f};
  f32x4 acc[4][4];
#pragma unroll
  for (int i = 0; i < 4; ++i)
#pragma unroll
    for (int j = 0; j < 4; ++j) acc[i][j] = z4;

  const int cf0 = tid, cf1 = 256 + tid;
  const int br0 = cf0 >> 2, bc0 = (cf0 & 3) * 8;
  const int br1 = cf1 >> 2, bc1 = (cf1 & 3) * 8;
  const __hip_bfloat16* bh0 = Bh + (n0 + br0) * K + bc0;
  const __hip_bfloat16* bh1 = Bh + (n0 + br1) * K + bc1;
  const __hip_bfloat16* bl0 = Bl + (n0 + br0) * K + bc0;
  const __hip_bfloat16* bl1 = Bl + (n0 + br1) * K + bc1;

  for (int k0 = 0; k0 < K; k0 += 32) {
    async16(bh0 + k0, Bsh + cf0 * 8);
    async16(bh1 + k0, Bsh + cf1 * 8);
    async16(bl0 + k0, Bsl + cf0 * 8);
    async16(bl1 + k0, Bsl + cf1 * 8);
#pragma unroll
    for (int it = 0; it < 4; ++it) {
      int c = it * 256 + tid, row = c >> 3, c4 = (c & 7) * 4;
      uint4 p = *(const uint4*)(Ap + (m0 + row) * K + k0 + c4);
      uint2 wh, wl;
      wh.x = (p.x & 0xffff) | ((p.y & 0xffff) << 16);
      wh.y = (p.z & 0xffff) | ((p.w & 0xffff) << 16);
      wl.x = (p.x >> 16) | (p.y & 0xffff0000u);
      wl.y = (p.z >> 16) | (p.w & 0xffff0000u);
      *(uint2*)(Ash + row * 32 + c4) = wh;
      *(uint2*)(Asl + row * 32 + c4) = wl;
    }
    __syncthreads();
    bf16x8 ah[4], al[4], bh[4], bl[4];
#pragma unroll
    for (int i = 0; i < 4; ++i) {
      ah[i] = *(const bf16x8*)(Ash + (wm + i * 16 + lo) * 32 + quad * 8);
      al[i] = *(const bf16x8*)(Asl + (wm + i * 16 + lo) * 32 + quad * 8);
      bh[i] = *(const bf16x8*)(Bsh + (wn + i * 16 + lo) * 32 + quad * 8);
      bl[i] = *(const bf16x8*)(Bsl + (wn + i * 16 + lo) * 32 + quad * 8);
    }
#pragma unroll
    for (int i = 0; i < 4; ++i)
#pragma unroll
      for (int j = 0; j < 4; ++j) {
        acc[i][j] = MFMA16(ah[i], bh[j], acc[i][j]);
        acc[i][j] = MFMA16(al[i], bh[j], acc[i][j]);
        acc[i][j] = MFMA16(ah[i], bl[j], acc[i][j]);
      }
    __syncthreads();
  }
#pragma unroll
  for (int i = 0; i < 4; ++i)
#pragma unroll
    for (int j = 0; j < 4; ++j)
#pragma unroll
      for (int r = 0; r < 4; ++r) {
        long row = m0 + wm + i * 16 + quad * 4 + r;
        long col = n0 + wn + j * 16 + lo;
        C[row * N + col] = acc[i][j][r];
      }
}

// ------------------------------------------------------------------- launcher
extern "C" void kernel_launch(void* const* d_in, const int* in_sizes, int n_in,
                              void* d_out, int out_size, void* d_ws, size_t ws_size,
                              hipStream_t stream) {
  (void)in_sizes; (void)n_in; (void)out_size; (void)ws_size;
  const int* positions = (const int*)d_in[0];
  const float* hidden = (const float*)d_in[1];
  const float* Wq = (const float*)d_in[2];
  const float* Wk = (const float*)d_in[3];
  const float* Wv = (const float*)d_in[4];
  const float* Wo = (const float*)d_in[5];
  const float* qw = (const float*)d_in[6];
  const float* kw = (const float*)d_in[7];
  float* out = (float*)d_out;
  char* ws = (char*)d_ws;

  // layout (bytes), total exactly 160 MiB:
  __hip_bfloat16* hid  = (__hip_bfloat16*)(ws + 0);           // 16 MB
  __hip_bfloat16* WqT  = (__hip_bfloat16*)(ws + 16777216);    // 32 MB
  __hip_bfloat16* WkT  = (__hip_bfloat16*)(ws + 50331648);    //  2 MB
  __hip_bfloat16* WvT  = (__hip_bfloat16*)(ws + 52428800);    //  2 MB
  float*          qf   = (float*)(ws + 54525952);             // 64 MB (T,16,256) fp32 -> packed -> o packed
  __hip_bfloat16* gate = (__hip_bfloat16*)(ws + 121634816);   // 32 MB (T,16,256)
  float*          kf   = (float*)(ws + 155189248);            //  8 MB (T,2,256) fp32
  __hip_bfloat16* vraw = (__hip_bfloat16*)(ws + 163577856);   //  4 MB -> end 167,772,160
  __hip_bfloat16* vT   = WkT;                                  // alias [48,52) MiB after k/v GEMMs
  __hip_bfloat16* kn   = vraw;                                 // alias vraw after V transpose
  __hip_bfloat16* WoTh = gate;                                 // alias gate region after attn
  __hip_bfloat16* WoTl = (__hip_bfloat16*)(ws + 138412032);    // gate region second half
  unsigned* qpk = (unsigned*)qf;

  // 1) casts / transposes
  cast_f32_bf16<<<dim3(8192), dim3(256), 0, stream>>>(hidden, hid, 2097152);
  transpose_cast<float><<<dim3(256, 64), dim3(256), 0, stream>>>(Wq, WqT, 2048, 8192);
  transpose_cast<float><<<dim3(16, 64), dim3(256), 0, stream>>>(Wk, WkT, 2048, 512);
  transpose_cast<float><<<dim3(16, 64), dim3(256), 0, stream>>>(Wv, WvT, 2048, 512);
  // 2) projections: q fp32 + gate bf16; k fp32; v bf16
  gemm_qg<<<dim3(64, 32), dim3(256), 0, stream>>>(hid, WqT, qf, gate, 4096, 8192, 2048);
  gemm_bt<1><<<dim3(4, 32), dim3(256), 0, stream>>>(hid, WkT, kf, 4096, 512, 2048);
  gemm_bt<0><<<dim3(4, 32), dim3(256), 0, stream>>>(hid, WvT, vraw, 4096, 512, 2048);
  // 3) V -> V^T (2,256,T), bf16 (must precede norm: kn aliases vraw)
  transpose_cast<__hip_bfloat16><<<dim3(16, 128), dim3(256), 0, stream>>>(vraw, vT, 4096, 512);
  // 4) RMSNorm + RoPE: q packed hi/lo in-place; k plain bf16 -> kn
  norm_rope_pack<<<dim3(4096, 18), dim3(256), 0, stream>>>(qf, kf, kn, positions, qw, kw);
  // 5) flash attention (balanced q-tile pairs); writes o packed hi/lo over q buffer
  attn_kernel<<<dim3(32, 16), dim3(256), 0, stream>>>(qpk, kn, vT, gate);
  // 6) Wo -> hi/lo transpose (into dead gate region), then 3-pass out GEMM
  transpose_split<<<dim3(64, 128), dim3(256), 0, stream>>>(Wo, WoTh, WoTl, 4096, 2048);
  gemm_out<<<dim3(16, 32), dim3(256), 0, stream>>>(qpk, WoTh, WoTl, out, 4096, 2048, 4096);
}

// Round 5
// 1123.986 us; speedup vs baseline: 1.6435x; 1.2775x over previous
//
#include <hip/hip_runtime.h>
#include <hip/hip_bf16.h>

// Qwen3.5 attention block: T=4096, H=2048, NH=16, NKV=2, HD=256, ROT=64
// bf16 MFMA (16x16x32) with fp32 accumulate; precision-critical intermediates
// kept fp32 or split into bf16 hi/lo pairs (packed ushort2 in 4B slots).
// K/V are pre-swizzled in HBM into the LDS image order so attn staging is
// coalesced async16 AND conflict-free on the LDS read side.

#define T_SZ 4096
#define H_SZ 2048
#define NH_SZ 16
#define NKV_SZ 2
#define HD_SZ 256
#define ATT_SCALE 0.0625f   // HD^-0.5
#define EPS_ 1e-6f

typedef __attribute__((ext_vector_type(8))) short bf16x8;   // 8 bf16 = 4 VGPRs
typedef __attribute__((ext_vector_type(4))) float f32x4;

#define MFMA16(a, b, c) __builtin_amdgcn_mfma_f32_16x16x32_bf16((a), (b), (c), 0, 0, 0)

__device__ __forceinline__ void async16(const void* g, void* l) {
  __builtin_amdgcn_global_load_lds((const __attribute__((address_space(1))) void*)g,
                                   (__attribute__((address_space(3))) void*)l,
                                   16, 0, 0);
}

__device__ __forceinline__ float to_f(float x) { return x; }
__device__ __forceinline__ float to_f(__hip_bfloat16 x) { return __bfloat162float(x); }

union BfBits { __hip_bfloat16 h; unsigned short u; };

__device__ __forceinline__ unsigned short bf16_bits(__hip_bfloat16 h) {
  BfBits t; t.h = h; return t.u;
}

__device__ __forceinline__ unsigned pack_hilo(float v) {
  __hip_bfloat16 hi = __float2bfloat16(v);
  float rem = v - __bfloat162float(hi);
  __hip_bfloat16 lo = __float2bfloat16(rem);
  return (unsigned)bf16_bits(hi) | ((unsigned)bf16_bits(lo) << 16);
}

// ---------------------------------------------------------------- cast hidden
__global__ __launch_bounds__(256) void cast_f32_bf16(const float* __restrict__ in,
                                                     __hip_bfloat16* __restrict__ out,
                                                     int n4) {
  int i = blockIdx.x * 256 + threadIdx.x;
  if (i >= n4) return;
  float4 v = ((const float4*)in)[i];
  union { __hip_bfloat16 h[4]; uint2 u; } t;
  t.h[0] = __float2bfloat16(v.x);
  t.h[1] = __float2bfloat16(v.y);
  t.h[2] = __float2bfloat16(v.z);
  t.h[3] = __float2bfloat16(v.w);
  ((uint2*)out)[i] = t.u;
}

// ------------------------------------------------------- transpose (+cast bf16)
template <typename TIN>
__global__ __launch_bounds__(256) void transpose_cast(const TIN* __restrict__ in,
                                                      __hip_bfloat16* __restrict__ out,
                                                      int R, int C) {
  __shared__ TIN tile[32][33];
  int c0 = blockIdx.x * 32, r0 = blockIdx.y * 32;
  int tx = threadIdx.x & 31, ty = threadIdx.x >> 5;
#pragma unroll
  for (int i = 0; i < 32; i += 8)
    tile[ty + i][tx] = in[(long)(r0 + ty + i) * C + c0 + tx];
  __syncthreads();
#pragma unroll
  for (int i = 0; i < 32; i += 8)
    out[(long)(c0 + ty + i) * R + r0 + tx] = __float2bfloat16(to_f(tile[tx][ty + i]));
}

// transpose fp32 -> bf16 hi + bf16 lo (for Wo split)
__global__ __launch_bounds__(256) void transpose_split(const float* __restrict__ in,
                                                       __hip_bfloat16* __restrict__ oh,
                                                       __hip_bfloat16* __restrict__ ol,
                                                       int R, int C) {
  __shared__ float tile[32][33];
  int c0 = blockIdx.x * 32, r0 = blockIdx.y * 32;
  int tx = threadIdx.x & 31, ty = threadIdx.x >> 5;
#pragma unroll
  for (int i = 0; i < 32; i += 8)
    tile[ty + i][tx] = in[(long)(r0 + ty + i) * C + c0 + tx];
  __syncthreads();
#pragma unroll
  for (int i = 0; i < 32; i += 8) {
    float v = tile[tx][ty + i];
    __hip_bfloat16 hi = __float2bfloat16(v);
    __hip_bfloat16 lo = __float2bfloat16(v - __bfloat162float(hi));
    long idx = (long)(c0 + ty + i) * R + r0 + tx;
    oh[idx] = hi;
    ol[idx] = lo;
  }
}

// ------------------------------------------------------------------ GEMM (B^T)
template <int OUTF32>
__global__ __launch_bounds__(256) void gemm_bt(const __hip_bfloat16* __restrict__ A,
                                               const __hip_bfloat16* __restrict__ BT,
                                               void* __restrict__ Cp,
                                               int M, int N, int K) {
  __shared__ __align__(16) __hip_bfloat16 As[128 * 32];
  __shared__ __align__(16) __hip_bfloat16 Bs[128 * 32];
  const int tid = threadIdx.x;
  const int wid = tid >> 6, lane = tid & 63;
  const int lo = lane & 15, quad = lane >> 4;
  const long m0 = (long)blockIdx.y * 128, n0 = (long)blockIdx.x * 128;
  const int wm = (wid >> 1) * 64, wn = (wid & 1) * 64;
  const f32x4 z4 = {0.f, 0.f, 0.f, 0.f};
  f32x4 acc[4][4];
#pragma unroll
  for (int i = 0; i < 4; ++i)
#pragma unroll
    for (int j = 0; j < 4; ++j) acc[i][j] = z4;

  const int cf0 = tid, cf1 = 256 + tid;
  const int r0_ = cf0 >> 2, c0_ = (cf0 & 3) * 8;
  const int r1_ = cf1 >> 2, c1_ = (cf1 & 3) * 8;
  const __hip_bfloat16* a0 = A + (m0 + r0_) * K + c0_;
  const __hip_bfloat16* a1 = A + (m0 + r1_) * K + c1_;
  const __hip_bfloat16* b0 = BT + (n0 + r0_) * K + c0_;
  const __hip_bfloat16* b1 = BT + (n0 + r1_) * K + c1_;

  for (int k0 = 0; k0 < K; k0 += 32) {
    async16(a0 + k0, As + cf0 * 8);
    async16(a1 + k0, As + cf1 * 8);
    async16(b0 + k0, Bs + cf0 * 8);
    async16(b1 + k0, Bs + cf1 * 8);
    __syncthreads();
    bf16x8 af[4], bfv[4];
#pragma unroll
    for (int i = 0; i < 4; ++i)
      af[i] = *(const bf16x8*)(As + (wm + i * 16 + lo) * 32 + quad * 8);
#pragma unroll
    for (int i = 0; i < 4; ++i)
      bfv[i] = *(const bf16x8*)(Bs + (wn + i * 16 + lo) * 32 + quad * 8);
#pragma unroll
    for (int i = 0; i < 4; ++i)
#pragma unroll
      for (int j = 0; j < 4; ++j) acc[i][j] = MFMA16(af[i], bfv[j], acc[i][j]);
    __syncthreads();
  }
#pragma unroll
  for (int i = 0; i < 4; ++i)
#pragma unroll
    for (int j = 0; j < 4; ++j)
#pragma unroll
      for (int r = 0; r < 4; ++r) {
        long row = m0 + wm + i * 16 + quad * 4 + r;
        long col = n0 + wn + j * 16 + lo;
        float v = acc[i][j][r];
        if (OUTF32)
          ((float*)Cp)[row * N + col] = v;
        else
          ((__hip_bfloat16*)Cp)[row * N + col] = __float2bfloat16(v);
      }
}

// ------------------------------------------- Wq GEMM with q(fp32)/gate(bf16) split
__global__ __launch_bounds__(256) void gemm_qg(const __hip_bfloat16* __restrict__ A,
                                               const __hip_bfloat16* __restrict__ BT,
                                               float* __restrict__ qout,
                                               __hip_bfloat16* __restrict__ gate,
                                               int M, int N, int K) {
  __shared__ __align__(16) __hip_bfloat16 As[128 * 32];
  __shared__ __align__(16) __hip_bfloat16 Bs[128 * 32];
  const int tid = threadIdx.x;
  const int wid = tid >> 6, lane = tid & 63;
  const int lo = lane & 15, quad = lane >> 4;
  const long m0 = (long)blockIdx.y * 128, n0 = (long)blockIdx.x * 128;
  const int wm = (wid >> 1) * 64, wn = (wid & 1) * 64;
  const f32x4 z4 = {0.f, 0.f, 0.f, 0.f};
  f32x4 acc[4][4];
#pragma unroll
  for (int i = 0; i < 4; ++i)
#pragma unroll
    for (int j = 0; j < 4; ++j) acc[i][j] = z4;

  const int cf0 = tid, cf1 = 256 + tid;
  const int r0_ = cf0 >> 2, c0_ = (cf0 & 3) * 8;
  const int r1_ = cf1 >> 2, c1_ = (cf1 & 3) * 8;
  const __hip_bfloat16* a0 = A + (m0 + r0_) * K + c0_;
  const __hip_bfloat16* a1 = A + (m0 + r1_) * K + c1_;
  const __hip_bfloat16* b0 = BT + (n0 + r0_) * K + c0_;
  const __hip_bfloat16* b1 = BT + (n0 + r1_) * K + c1_;

  for (int k0 = 0; k0 < K; k0 += 32) {
    async16(a0 + k0, As + cf0 * 8);
    async16(a1 + k0, As + cf1 * 8);
    async16(b0 + k0, Bs + cf0 * 8);
    async16(b1 + k0, Bs + cf1 * 8);
    __syncthreads();
    bf16x8 af[4], bfv[4];
#pragma unroll
    for (int i = 0; i < 4; ++i)
      af[i] = *(const bf16x8*)(As + (wm + i * 16 + lo) * 32 + quad * 8);
#pragma unroll
    for (int i = 0; i < 4; ++i)
      bfv[i] = *(const bf16x8*)(Bs + (wn + i * 16 + lo) * 32 + quad * 8);
#pragma unroll
    for (int i = 0; i < 4; ++i)
#pragma unroll
      for (int j = 0; j < 4; ++j) acc[i][j] = MFMA16(af[i], bfv[j], acc[i][j]);
    __syncthreads();
  }
#pragma unroll
  for (int i = 0; i < 4; ++i)
#pragma unroll
    for (int j = 0; j < 4; ++j)
#pragma unroll
      for (int r = 0; r < 4; ++r) {
        long row = m0 + wm + i * 16 + quad * 4 + r;  // token t
        long col = n0 + wn + j * 16 + lo;            // n in [0,8192)
        int head = (int)(col >> 9), c = (int)(col & 511);
        float v = acc[i][j][r];
        if (c < 256)
          qout[(row * NH_SZ + head) * 256 + c] = v;
        else
          gate[(row * NH_SZ + head) * 256 + (c - 256)] = __float2bfloat16(v);
      }
}

// --------------------------------------- V -> swizzled LDS-image layout
// vraw (T,2,256) -> vsw[kvh][ktt][c=kv/8][hd=256][e=kv%8]; grid (64, 2).
__global__ __launch_bounds__(256) void v_swizzle(const __hip_bfloat16* __restrict__ vraw,
                                                 __hip_bfloat16* __restrict__ vsw) {
  const int ktt = blockIdx.x, kvh = blockIdx.y, tid = threadIdx.x;
  __shared__ __hip_bfloat16 L[64 * 264];
#pragma unroll
  for (int it = 0; it < 8; ++it) {
    int cf = it * 256 + tid;           // 2048 chunks of 8 elems
    int kv = cf >> 5, d0 = (cf & 31) * 8;
    *(uint4*)&L[kv * 264 + d0] =
        *(const uint4*)&vraw[(((long)ktt * 64 + kv) * NKV_SZ + kvh) * 256 + d0];
  }
  __syncthreads();
#pragma unroll
  for (int it = 0; it < 8; ++it) {
    int cf = it * 256 + tid;           // c in [0,8), d in [0,256)
    int c = cf >> 8, d = cf & 255;
    union { __hip_bfloat16 h[8]; uint4 u; } t;
#pragma unroll
    for (int e = 0; e < 8; ++e) t.h[e] = L[(c * 8 + e) * 264 + d];
    *(uint4*)&vsw[((long)kvh * 64 + ktt) * 16384 + (long)(c * 256 + d) * 8] = t.u;
  }
}

// ---- RMSNorm + RoPE from fp32; q: packed hi/lo in-place, k: swizzled bf16
// ksw[kvh][ktt][c=d/8][r=t%64][e=d%8]
__global__ __launch_bounds__(256) void norm_rope_pack(float* __restrict__ qbuf,
                                                      const float* __restrict__ kbuf,
                                                      __hip_bfloat16* __restrict__ ksw,
                                                      const int* __restrict__ pos,
                                                      const float* __restrict__ qw,
                                                      const float* __restrict__ kw) {
  const int t = blockIdx.x, h = blockIdx.y, d = threadIdx.x;
  __shared__ float buf[256];
  __shared__ float red[4];
  const float* ptr;
  const float* w;
  if (h < NH_SZ) {
    ptr = qbuf + ((long)t * NH_SZ + h) * 256;
    w = qw;
  } else {
    ptr = kbuf + ((long)t * NKV_SZ + (h - NH_SZ)) * 256;
    w = kw;
  }
  float x = ptr[d];
  float s2 = x * x;
#pragma unroll
  for (int o = 32; o > 0; o >>= 1) s2 += __shfl_down(s2, o);
  if ((d & 63) == 0) red[d >> 6] = s2;
  __syncthreads();
  float tot = red[0] + red[1] + red[2] + red[3];
  float sc = rsqrtf(tot * (1.0f / 256.0f) + EPS_);
  buf[d] = x * sc * (1.0f + w[d]);
  __syncthreads();
  float outv;
  if (d < 64) {
    int i = d & 31;
    float p = (float)pos[(i % 3) * T_SZ + t];
    float fr = p * exp2f((float)i * (-0.72667177075661f));  // 1e7^(-i/32)
    float c, s;
    sincosf(fr, &s, &c);
    if (d < 32)
      outv = buf[d] * c - buf[d + 32] * s;
    else
      outv = buf[d] * c + buf[d - 32] * s;
  } else {
    outv = buf[d];
  }
  if (h < NH_SZ) {
    ((unsigned*)qbuf)[((long)t * NH_SZ + h) * 256 + d] = pack_hilo(outv);
  } else {
    int kv = h - NH_SZ;
    long ktt = t >> 6, r = t & 63;
    int c = d >> 3, e = d & 7;
    ksw[((((long)kv * 64 + ktt) * 32 + c) * 64 + r) * 8 + e] = __float2bfloat16(outv);
  }
}

// ------------------------------------------------------- flash causal attention
// Q packed hi/lo (T,16,256); Ksw/Vsw swizzled bf16; gate bf16.
// Output packed hi/lo written IN-PLACE over Q buffer.
// Grid (32,16): block p handles q-tiles p and 63-p (balanced: 65 iters total).
__global__ __launch_bounds__(256) void attn_kernel(unsigned* __restrict__ Qp,
                                                   const __hip_bfloat16* __restrict__ Ksw,
                                                   const __hip_bfloat16* __restrict__ Vsw,
                                                   const __hip_bfloat16* __restrict__ Gt) {
  const int p = blockIdx.x, h = blockIdx.y, kvh = h >> 3;
  const int tid = threadIdx.x, wid = tid >> 6, lane = tid & 63;
  const int lo = lane & 15, quad = lane >> 4;
  __shared__ __align__(16) __hip_bfloat16 Ks[32 * 512];   // [chunk=hd/8][kv=64][8]
  __shared__ __align__(16) __hip_bfloat16 Vs[8 * 2048];   // [chunk=kv/8][hd=256][8]
  __shared__ __align__(16) __hip_bfloat16 Ps[4][16 * 72]; // per-wave, stride 72

  __hip_bfloat16* myP = &Ps[wid][0];
  const f32x4 z4 = {0.f, 0.f, 0.f, 0.f};

  for (int side = 0; side < 2; ++side) {
    const int qt = side ? 63 - p : p;

    // Q fragments hi+lo (A-layout): row = lane&15, k = quad*8 + kc*32 + j
    bf16x8 qh[8], ql[8];
    {
      const unsigned* qp =
          Qp + ((long)(qt * 64 + wid * 16 + lo) * NH_SZ + h) * 256 + quad * 8;
#pragma unroll
      for (int kc = 0; kc < 8; ++kc) {
        uint4 p0 = *(const uint4*)(qp + kc * 32);
        uint4 p1 = *(const uint4*)(qp + kc * 32 + 4);
        bf16x8 a, b;
        a[0] = (short)(p0.x & 0xffff); b[0] = (short)(p0.x >> 16);
        a[1] = (short)(p0.y & 0xffff); b[1] = (short)(p0.y >> 16);
        a[2] = (short)(p0.z & 0xffff); b[2] = (short)(p0.z >> 16);
        a[3] = (short)(p0.w & 0xffff); b[3] = (short)(p0.w >> 16);
        a[4] = (short)(p1.x & 0xffff); b[4] = (short)(p1.x >> 16);
        a[5] = (short)(p1.y & 0xffff); b[5] = (short)(p1.y >> 16);
        a[6] = (short)(p1.z & 0xffff); b[6] = (short)(p1.z >> 16);
        a[7] = (short)(p1.w & 0xffff); b[7] = (short)(p1.w >> 16);
        qh[kc] = a; ql[kc] = b;
      }
    }

    f32x4 acc[16];
#pragma unroll
    for (int od = 0; od < 16; ++od) acc[od] = z4;
    float m_r[4], l_r[4];
#pragma unroll
    for (int r = 0; r < 4; ++r) { m_r[r] = -1e30f; l_r[r] = 0.f; }

    const int qrow_g = qt * 64 + wid * 16 + quad * 4;

    // stage K(0), V(0): fully coalesced (swizzled source = LDS image)
    {
      const __hip_bfloat16* kb = Ksw + ((long)kvh * 64 + 0) * 16384;
      const __hip_bfloat16* vb = Vsw + ((long)kvh * 64 + 0) * 16384;
#pragma unroll
      for (int j = 0; j < 8; ++j) {
        int c = j * 4 + wid;
        async16(kb + c * 512 + lane * 8, Ks + c * 512 + lane * 8);
      }
#pragma unroll
      for (int j = 0; j < 8; ++j) {
        int idx = j * 4 + wid;
        async16(vb + idx * 512 + lane * 8, Vs + idx * 512 + lane * 8);
      }
    }

    for (int kt = 0; kt <= qt; ++kt) {
      __syncthreads();  // staging of K(kt),V(kt) drained; prev-iter reads done
      // scores: 2-pass (Q_hi + Q_lo) x K
      f32x4 s[4];
#pragma unroll
      for (int ni = 0; ni < 4; ++ni) s[ni] = z4;
#pragma unroll
      for (int kc = 0; kc < 8; ++kc) {
        bf16x8 ah = qh[kc], al = ql[kc];
#pragma unroll
        for (int ni = 0; ni < 4; ++ni) {
          bf16x8 b = *(const bf16x8*)(Ks + (kc * 4 + quad) * 512 + (ni * 16 + lo) * 8);
          s[ni] = MFMA16(ah, b, s[ni]);
          s[ni] = MFMA16(al, b, s[ni]);
        }
      }
      // online softmax (VALU only)
      float sv[4][4];
#pragma unroll
      for (int ni = 0; ni < 4; ++ni) {
        int kcol = kt * 64 + ni * 16 + lo;
#pragma unroll
        for (int r = 0; r < 4; ++r) {
          float v = s[ni][r] * ATT_SCALE;
          sv[ni][r] = (kcol > qrow_g + r) ? -1e30f : v;
        }
      }
#pragma unroll
      for (int r = 0; r < 4; ++r) {
        float mx = fmaxf(fmaxf(sv[0][r], sv[1][r]), fmaxf(sv[2][r], sv[3][r]));
#pragma unroll
        for (int off = 1; off < 16; off <<= 1) mx = fmaxf(mx, __shfl_xor(mx, off));
        float mnew = fmaxf(m_r[r], mx);
        float alpha = __expf(m_r[r] - mnew);
        float su = 0.f;
#pragma unroll
        for (int ni = 0; ni < 4; ++ni) {
          float e = __expf(sv[ni][r] - mnew);
          sv[ni][r] = e;
          su += e;
        }
#pragma unroll
        for (int off = 1; off < 16; off <<= 1) su += __shfl_xor(su, off);
        l_r[r] = l_r[r] * alpha + su;
        m_r[r] = mnew;
#pragma unroll
        for (int od = 0; od < 16; ++od) acc[od][r] *= alpha;
      }
      // write P to own-wave LDS (no barrier needed: per-wave buffer)
#pragma unroll
      for (int ni = 0; ni < 4; ++ni)
#pragma unroll
        for (int r = 0; r < 4; ++r)
          myP[(quad * 4 + r) * 72 + ni * 16 + lo] = __float2bfloat16(sv[ni][r]);
      // O += P V
#pragma unroll
      for (int kc2 = 0; kc2 < 2; ++kc2) {
        bf16x8 ap = *(const bf16x8*)(myP + lo * 72 + kc2 * 32 + quad * 8);
#pragma unroll
        for (int od = 0; od < 16; ++od) {
          bf16x8 bv = *(const bf16x8*)(Vs + (kc2 * 4 + quad) * 2048 + (od * 16 + lo) * 8);
          acc[od] = MFMA16(ap, bv, acc[od]);
        }
      }
      __syncthreads();  // all waves done reading Ks/Vs
      if (kt < qt) {
        const __hip_bfloat16* kb = Ksw + ((long)kvh * 64 + kt + 1) * 16384;
        const __hip_bfloat16* vb = Vsw + ((long)kvh * 64 + kt + 1) * 16384;
#pragma unroll
        for (int j = 0; j < 8; ++j) {
          int c = j * 4 + wid;
          async16(kb + c * 512 + lane * 8, Ks + c * 512 + lane * 8);
        }
#pragma unroll
        for (int j = 0; j < 8; ++j) {
          int idx = j * 4 + wid;
          async16(vb + idx * 512 + lane * 8, Vs + idx * 512 + lane * 8);
        }
      }
    }

    // epilogue: O /= l, * sigmoid(gate) fp32, write packed hi/lo in-place over Q
#pragma unroll
    for (int od = 0; od < 16; ++od)
#pragma unroll
      for (int r = 0; r < 4; ++r) {
        int trow = qt * 64 + wid * 16 + quad * 4 + r;
        int col = od * 16 + lo;
        long idx = ((long)trow * NH_SZ + h) * 256 + col;
        float g = __bfloat162float(Gt[idx]);
        float sig = 1.0f / (1.0f + expf(-g));
        float v = (acc[od][r] / l_r[r]) * sig;
        Qp[idx] = pack_hilo(v);
      }
  }
}

// ------------------------------- out GEMM: A packed hi/lo, B hi/lo, 3-pass, fp32 out
__global__ __launch_bounds__(256) void gemm_out(const unsigned* __restrict__ Ap,
                                                const __hip_bfloat16* __restrict__ Bh,
                                                const __hip_bfloat16* __restrict__ Bl,
                                                float* __restrict__ C,
                                                int M, int N, int K) {
  __shared__ __align__(16) __hip_bfloat16 Ash[128 * 32];
  __shared__ __align__(16) __hip_bfloat16 Asl[128 * 32];
  __shared__ __align__(16) __hip_bfloat16 Bsh[128 * 32];
  __shared__ __align__(16) __hip_bfloat16 Bsl[128 * 32];
  const int tid = threadIdx.x;
  const int wid = tid >> 6, lane = tid & 63;
  const int lo = lane & 15, quad = lane >> 4;
  const long m0 = (long)blockIdx.y * 128, n0 = (long)blockIdx.x * 128;
  const int wm = (wid >> 1) * 64, wn = (wid & 1) * 64;
  const f32x4 z4 = {0.f, 0.f, 0.f, 0.f};
  f32x4 acc[4][4];
#pragma unroll
  for (int i = 0; i < 4; ++i)
#pragma unroll
    for (int j = 0; j < 4; ++j) acc[i][j] = z4;

  const int cf0 = tid, cf1 = 256 + tid;
  const int br0 = cf0 >> 2, bc0 = (cf0 & 3) * 8;
  const int br1 = cf1 >> 2, bc1 = (cf1 & 3) * 8;
  const __hip_bfloat16* bh0 = Bh + (n0 + br0) * K + bc0;
  const __hip_bfloat16* bh1 = Bh + (n0 + br1) * K + bc1;
  const __hip_bfloat16* bl0 = Bl + (n0 + br0) * K + bc0;
  const __hip_bfloat16* bl1 = Bl + (n0 + br1) * K + bc1;

  for (int k0 = 0; k0 < K; k0 += 32) {
    async16(bh0 + k0, Bsh + cf0 * 8);
    async16(bh1 + k0, Bsh + cf1 * 8);
    async16(bl0 + k0, Bsl + cf0 * 8);
    async16(bl1 + k0, Bsl + cf1 * 8);
#pragma unroll
    for (int it = 0; it < 4; ++it) {
      int c = it * 256 + tid, row = c >> 3, c4 = (c & 7) * 4;
      uint4 p = *(const uint4*)(Ap + (m0 + row) * K + k0 + c4);
      uint2 wh, wl;
      wh.x = (p.x & 0xffff) | ((p.y & 0xffff) << 16);
      wh.y = (p.z & 0xffff) | ((p.w & 0xffff) << 16);
      wl.x = (p.x >> 16) | (p.y & 0xffff0000u);
      wl.y = (p.z >> 16) | (p.w & 0xffff0000u);
      *(uint2*)(Ash + row * 32 + c4) = wh;
      *(uint2*)(Asl + row * 32 + c4) = wl;
    }
    __syncthreads();
    bf16x8 ah[4], al[4], bh[4], bl[4];
#pragma unroll
    for (int i = 0; i < 4; ++i) {
      ah[i] = *(const bf16x8*)(Ash + (wm + i * 16 + lo) * 32 + quad * 8);
      al[i] = *(const bf16x8*)(Asl + (wm + i * 16 + lo) * 32 + quad * 8);
      bh[i] = *(const bf16x8*)(Bsh + (wn + i * 16 + lo) * 32 + quad * 8);
      bl[i] = *(const bf16x8*)(Bsl + (wn + i * 16 + lo) * 32 + quad * 8);
    }
#pragma unroll
    for (int i = 0; i < 4; ++i)
#pragma unroll
      for (int j = 0; j < 4; ++j) {
        acc[i][j] = MFMA16(ah[i], bh[j], acc[i][j]);
        acc[i][j] = MFMA16(al[i], bh[j], acc[i][j]);
        acc[i][j] = MFMA16(ah[i], bl[j], acc[i][j]);
      }
    __syncthreads();
  }
#pragma unroll
  for (int i = 0; i < 4; ++i)
#pragma unroll
    for (int j = 0; j < 4; ++j)
#pragma unroll
      for (int r = 0; r < 4; ++r) {
        long row = m0 + wm + i * 16 + quad * 4 + r;
        long col = n0 + wn + j * 16 + lo;
        C[row * N + col] = acc[i][j][r];
      }
}

// ------------------------------------------------------------------- launcher
extern "C" void kernel_launch(void* const* d_in, const int* in_sizes, int n_in,
                              void* d_out, int out_size, void* d_ws, size_t ws_size,
                              hipStream_t stream) {
  (void)in_sizes; (void)n_in; (void)out_size; (void)ws_size;
  const int* positions = (const int*)d_in[0];
  const float* hidden = (const float*)d_in[1];
  const float* Wq = (const float*)d_in[2];
  const float* Wk = (const float*)d_in[3];
  const float* Wv = (const float*)d_in[4];
  const float* Wo = (const float*)d_in[5];
  const float* qw = (const float*)d_in[6];
  const float* kw = (const float*)d_in[7];
  float* out = (float*)d_out;
  char* ws = (char*)d_ws;

  // layout (bytes), total exactly 160 MiB:
  __hip_bfloat16* hid  = (__hip_bfloat16*)(ws + 0);           // 16 MB (dead after GEMMs)
  __hip_bfloat16* WqT  = (__hip_bfloat16*)(ws + 16777216);    // 32 MB
  __hip_bfloat16* WkT  = (__hip_bfloat16*)(ws + 50331648);    //  2 MB
  __hip_bfloat16* WvT  = (__hip_bfloat16*)(ws + 52428800);    //  2 MB
  float*          qf   = (float*)(ws + 54525952);             // 64 MB fp32 q -> packed -> o packed
  __hip_bfloat16* gate = (__hip_bfloat16*)(ws + 121634816);   // 32 MB (T,16,256)
  float*          kf   = (float*)(ws + 155189248);            //  8 MB (T,2,256) fp32
  __hip_bfloat16* vraw = (__hip_bfloat16*)(ws + 163577856);   //  4 MB -> end 167,772,160
  __hip_bfloat16* Ksw  = WkT;                                  // alias 4 MB [WkT+WvT] after k/v GEMMs
  __hip_bfloat16* Vsw  = hid;                                  // alias 4 MB of hid after GEMMs
  __hip_bfloat16* WoTh = gate;                                 // alias gate region after attn
  __hip_bfloat16* WoTl = (__hip_bfloat16*)(ws + 138412032);    // gate region second half
  unsigned* qpk = (unsigned*)qf;

  // 1) casts / transposes
  cast_f32_bf16<<<dim3(8192), dim3(256), 0, stream>>>(hidden, hid, 2097152);
  transpose_cast<float><<<dim3(256, 64), dim3(256), 0, stream>>>(Wq, WqT, 2048, 8192);
  transpose_cast<float><<<dim3(16, 64), dim3(256), 0, stream>>>(Wk, WkT, 2048, 512);
  transpose_cast<float><<<dim3(16, 64), dim3(256), 0, stream>>>(Wv, WvT, 2048, 512);
  // 2) projections: q fp32 + gate bf16; k fp32; v bf16
  gemm_qg<<<dim3(64, 32), dim3(256), 0, stream>>>(hid, WqT, qf, gate, 4096, 8192, 2048);
  gemm_bt<1><<<dim3(4, 32), dim3(256), 0, stream>>>(hid, WkT, kf, 4096, 512, 2048);
  gemm_bt<0><<<dim3(4, 32), dim3(256), 0, stream>>>(hid, WvT, vraw, 4096, 512, 2048);
  // 3) V -> swizzled (after GEMMs: Vsw aliases hid)
  v_swizzle<<<dim3(64, 2), dim3(256), 0, stream>>>(vraw, Vsw);
  // 4) RMSNorm + RoPE: q packed hi/lo in-place; k swizzled bf16 -> Ksw
  norm_rope_pack<<<dim3(4096, 18), dim3(256), 0, stream>>>(qf, kf, Ksw, positions, qw, kw);
  // 5) flash attention (balanced q-tile pairs); writes o packed hi/lo over q buffer
  attn_kernel<<<dim3(32, 16), dim3(256), 0, stream>>>(qpk, Ksw, Vsw, gate);
  // 6) Wo -> hi/lo transpose (into dead gate region), then 3-pass out GEMM
  transpose_split<<<dim3(64, 128), dim3(256), 0, stream>>>(Wo, WoTh, WoTl, 4096, 2048);
  gemm_out<<<dim3(16, 32), dim3(256), 0, stream>>>(qpk, WoTh, WoTl, out, 4096, 2048, 4096);
}

// Round 6
// 985.211 us; speedup vs baseline: 1.8750x; 1.1409x over previous
//
#include <hip/hip_runtime.h>
#include <hip/hip_bf16.h>

// Qwen3.5 attention block: T=4096, H=2048, NH=16, NKV=2, HD=256, ROT=64
// bf16 MFMA (16x16x32) with fp32 accumulate; precision-critical intermediates
// kept fp32 or split into bf16 hi/lo pairs (packed ushort2 in 4B slots).
// K/V pre-swizzled in HBM into LDS image order (coalesced async16 staging +
// conflict-free LDS reads). Attention uses fixed-max softmax (scores provably
// bounded: |s|<=36, exp(s-18) safe in fp32; constant cancels in normalization).

#define T_SZ 4096
#define H_SZ 2048
#define NH_SZ 16
#define NKV_SZ 2
#define HD_SZ 256
#define ATT_SCALE 0.0625f   // HD^-0.5
#define SOFT_M 18.0f        // fixed softmax shift
#define EPS_ 1e-6f

typedef __attribute__((ext_vector_type(8))) short bf16x8;   // 8 bf16 = 4 VGPRs
typedef __attribute__((ext_vector_type(4))) float f32x4;

#define MFMA16(a, b, c) __builtin_amdgcn_mfma_f32_16x16x32_bf16((a), (b), (c), 0, 0, 0)

__device__ __forceinline__ void async16(const void* g, void* l) {
  __builtin_amdgcn_global_load_lds((const __attribute__((address_space(1))) void*)g,
                                   (__attribute__((address_space(3))) void*)l,
                                   16, 0, 0);
}

__device__ __forceinline__ float to_f(float x) { return x; }
__device__ __forceinline__ float to_f(__hip_bfloat16 x) { return __bfloat162float(x); }

union BfBits { __hip_bfloat16 h; unsigned short u; };

__device__ __forceinline__ unsigned short bf16_bits(__hip_bfloat16 h) {
  BfBits t; t.h = h; return t.u;
}

__device__ __forceinline__ unsigned pack_hilo(float v) {
  __hip_bfloat16 hi = __float2bfloat16(v);
  float rem = v - __bfloat162float(hi);
  __hip_bfloat16 lo = __float2bfloat16(rem);
  return (unsigned)bf16_bits(hi) | ((unsigned)bf16_bits(lo) << 16);
}

// ---------------------------------------------------------------- cast hidden
__global__ __launch_bounds__(256) void cast_f32_bf16(const float* __restrict__ in,
                                                     __hip_bfloat16* __restrict__ out,
                                                     int n4) {
  int i = blockIdx.x * 256 + threadIdx.x;
  if (i >= n4) return;
  float4 v = ((const float4*)in)[i];
  union { __hip_bfloat16 h[4]; uint2 u; } t;
  t.h[0] = __float2bfloat16(v.x);
  t.h[1] = __float2bfloat16(v.y);
  t.h[2] = __float2bfloat16(v.z);
  t.h[3] = __float2bfloat16(v.w);
  ((uint2*)out)[i] = t.u;
}

// ------------------------------------------------------- transpose (+cast bf16)
template <typename TIN>
__global__ __launch_bounds__(256) void transpose_cast(const TIN* __restrict__ in,
                                                      __hip_bfloat16* __restrict__ out,
                                                      int R, int C) {
  __shared__ TIN tile[32][33];
  int c0 = blockIdx.x * 32, r0 = blockIdx.y * 32;
  int tx = threadIdx.x & 31, ty = threadIdx.x >> 5;
#pragma unroll
  for (int i = 0; i < 32; i += 8)
    tile[ty + i][tx] = in[(long)(r0 + ty + i) * C + c0 + tx];
  __syncthreads();
#pragma unroll
  for (int i = 0; i < 32; i += 8)
    out[(long)(c0 + ty + i) * R + r0 + tx] = __float2bfloat16(to_f(tile[tx][ty + i]));
}

// ------------------------------------------------------------------ GEMM (B^T)
template <int OUTF32>
__global__ __launch_bounds__(256) void gemm_bt(const __hip_bfloat16* __restrict__ A,
                                               const __hip_bfloat16* __restrict__ BT,
                                               void* __restrict__ Cp,
                                               int M, int N, int K) {
  __shared__ __align__(16) __hip_bfloat16 As[128 * 32];
  __shared__ __align__(16) __hip_bfloat16 Bs[128 * 32];
  const int tid = threadIdx.x;
  const int wid = tid >> 6, lane = tid & 63;
  const int lo = lane & 15, quad = lane >> 4;
  const long m0 = (long)blockIdx.y * 128, n0 = (long)blockIdx.x * 128;
  const int wm = (wid >> 1) * 64, wn = (wid & 1) * 64;
  const f32x4 z4 = {0.f, 0.f, 0.f, 0.f};
  f32x4 acc[4][4];
#pragma unroll
  for (int i = 0; i < 4; ++i)
#pragma unroll
    for (int j = 0; j < 4; ++j) acc[i][j] = z4;

  const int cf0 = tid, cf1 = 256 + tid;
  const int r0_ = cf0 >> 2, c0_ = (cf0 & 3) * 8;
  const int r1_ = cf1 >> 2, c1_ = (cf1 & 3) * 8;
  const __hip_bfloat16* a0 = A + (m0 + r0_) * K + c0_;
  const __hip_bfloat16* a1 = A + (m0 + r1_) * K + c1_;
  const __hip_bfloat16* b0 = BT + (n0 + r0_) * K + c0_;
  const __hip_bfloat16* b1 = BT + (n0 + r1_) * K + c1_;

  for (int k0 = 0; k0 < K; k0 += 32) {
    async16(a0 + k0, As + cf0 * 8);
    async16(a1 + k0, As + cf1 * 8);
    async16(b0 + k0, Bs + cf0 * 8);
    async16(b1 + k0, Bs + cf1 * 8);
    __syncthreads();
    bf16x8 af[4], bfv[4];
#pragma unroll
    for (int i = 0; i < 4; ++i)
      af[i] = *(const bf16x8*)(As + (wm + i * 16 + lo) * 32 + quad * 8);
#pragma unroll
    for (int i = 0; i < 4; ++i)
      bfv[i] = *(const bf16x8*)(Bs + (wn + i * 16 + lo) * 32 + quad * 8);
#pragma unroll
    for (int i = 0; i < 4; ++i)
#pragma unroll
      for (int j = 0; j < 4; ++j) acc[i][j] = MFMA16(af[i], bfv[j], acc[i][j]);
    __syncthreads();
  }
#pragma unroll
  for (int i = 0; i < 4; ++i)
#pragma unroll
    for (int j = 0; j < 4; ++j)
#pragma unroll
      for (int r = 0; r < 4; ++r) {
        long row = m0 + wm + i * 16 + quad * 4 + r;
        long col = n0 + wn + j * 16 + lo;
        float v = acc[i][j][r];
        if (OUTF32)
          ((float*)Cp)[row * N + col] = v;
        else
          ((__hip_bfloat16*)Cp)[row * N + col] = __float2bfloat16(v);
      }
}

// ------------------------------------------- Wq GEMM with q(fp32)/gate(bf16) split
__global__ __launch_bounds__(256) void gemm_qg(const __hip_bfloat16* __restrict__ A,
                                               const __hip_bfloat16* __restrict__ BT,
                                               float* __restrict__ qout,
                                               __hip_bfloat16* __restrict__ gate,
                                               int M, int N, int K) {
  __shared__ __align__(16) __hip_bfloat16 As[128 * 32];
  __shared__ __align__(16) __hip_bfloat16 Bs[128 * 32];
  const int tid = threadIdx.x;
  const int wid = tid >> 6, lane = tid & 63;
  const int lo = lane & 15, quad = lane >> 4;
  const long m0 = (long)blockIdx.y * 128, n0 = (long)blockIdx.x * 128;
  const int wm = (wid >> 1) * 64, wn = (wid & 1) * 64;
  const f32x4 z4 = {0.f, 0.f, 0.f, 0.f};
  f32x4 acc[4][4];
#pragma unroll
  for (int i = 0; i < 4; ++i)
#pragma unroll
    for (int j = 0; j < 4; ++j) acc[i][j] = z4;

  const int cf0 = tid, cf1 = 256 + tid;
  const int r0_ = cf0 >> 2, c0_ = (cf0 & 3) * 8;
  const int r1_ = cf1 >> 2, c1_ = (cf1 & 3) * 8;
  const __hip_bfloat16* a0 = A + (m0 + r0_) * K + c0_;
  const __hip_bfloat16* a1 = A + (m0 + r1_) * K + c1_;
  const __hip_bfloat16* b0 = BT + (n0 + r0_) * K + c0_;
  const __hip_bfloat16* b1 = BT + (n0 + r1_) * K + c1_;

  for (int k0 = 0; k0 < K; k0 += 32) {
    async16(a0 + k0, As + cf0 * 8);
    async16(a1 + k0, As + cf1 * 8);
    async16(b0 + k0, Bs + cf0 * 8);
    async16(b1 + k0, Bs + cf1 * 8);
    __syncthreads();
    bf16x8 af[4], bfv[4];
#pragma unroll
    for (int i = 0; i < 4; ++i)
      af[i] = *(const bf16x8*)(As + (wm + i * 16 + lo) * 32 + quad * 8);
#pragma unroll
    for (int i = 0; i < 4; ++i)
      bfv[i] = *(const bf16x8*)(Bs + (wn + i * 16 + lo) * 32 + quad * 8);
#pragma unroll
    for (int i = 0; i < 4; ++i)
#pragma unroll
      for (int j = 0; j < 4; ++j) acc[i][j] = MFMA16(af[i], bfv[j], acc[i][j]);
    __syncthreads();
  }
#pragma unroll
  for (int i = 0; i < 4; ++i)
#pragma unroll
    for (int j = 0; j < 4; ++j)
#pragma unroll
      for (int r = 0; r < 4; ++r) {
        long row = m0 + wm + i * 16 + quad * 4 + r;  // token t
        long col = n0 + wn + j * 16 + lo;            // n in [0,8192)
        int head = (int)(col >> 9), c = (int)(col & 511);
        float v = acc[i][j][r];
        if (c < 256)
          qout[(row * NH_SZ + head) * 256 + c] = v;
        else
          gate[(row * NH_SZ + head) * 256 + (c - 256)] = __float2bfloat16(v);
      }
}

// --------------------------------------- V -> swizzled LDS-image layout
// vraw (T,2,256) -> vsw[kvh][ktt][c=kv/8][hd=256][e=kv%8]; grid (64, 2).
__global__ __launch_bounds__(256) void v_swizzle(const __hip_bfloat16* __restrict__ vraw,
                                                 __hip_bfloat16* __restrict__ vsw) {
  const int ktt = blockIdx.x, kvh = blockIdx.y, tid = threadIdx.x;
  __shared__ __hip_bfloat16 L[64 * 264];
#pragma unroll
  for (int it = 0; it < 8; ++it) {
    int cf = it * 256 + tid;           // 2048 chunks of 8 elems
    int kv = cf >> 5, d0 = (cf & 31) * 8;
    *(uint4*)&L[kv * 264 + d0] =
        *(const uint4*)&vraw[(((long)ktt * 64 + kv) * NKV_SZ + kvh) * 256 + d0];
  }
  __syncthreads();
#pragma unroll
  for (int it = 0; it < 8; ++it) {
    int cf = it * 256 + tid;           // c in [0,8), d in [0,256)
    int c = cf >> 8, d = cf & 255;
    union { __hip_bfloat16 h[8]; uint4 u; } t;
#pragma unroll
    for (int e = 0; e < 8; ++e) t.h[e] = L[(c * 8 + e) * 264 + d];
    *(uint4*)&vsw[((long)kvh * 64 + ktt) * 16384 + (long)(c * 256 + d) * 8] = t.u;
  }
}

// ---- RMSNorm + RoPE from fp32; q: packed hi/lo in-place, k: swizzled bf16
// ksw[kvh][ktt][c=d/8][r=t%64][e=d%8]
__global__ __launch_bounds__(256) void norm_rope_pack(float* __restrict__ qbuf,
                                                      const float* __restrict__ kbuf,
                                                      __hip_bfloat16* __restrict__ ksw,
                                                      const int* __restrict__ pos,
                                                      const float* __restrict__ qw,
                                                      const float* __restrict__ kw) {
  const int t = blockIdx.x, h = blockIdx.y, d = threadIdx.x;
  __shared__ float buf[256];
  __shared__ float red[4];
  const float* ptr;
  const float* w;
  if (h < NH_SZ) {
    ptr = qbuf + ((long)t * NH_SZ + h) * 256;
    w = qw;
  } else {
    ptr = kbuf + ((long)t * NKV_SZ + (h - NH_SZ)) * 256;
    w = kw;
  }
  float x = ptr[d];
  float s2 = x * x;
#pragma unroll
  for (int o = 32; o > 0; o >>= 1) s2 += __shfl_down(s2, o);
  if ((d & 63) == 0) red[d >> 6] = s2;
  __syncthreads();
  float tot = red[0] + red[1] + red[2] + red[3];
  float sc = rsqrtf(tot * (1.0f / 256.0f) + EPS_);
  buf[d] = x * sc * (1.0f + w[d]);
  __syncthreads();
  float outv;
  if (d < 64) {
    int i = d & 31;
    float p = (float)pos[(i % 3) * T_SZ + t];
    float fr = p * exp2f((float)i * (-0.72667177075661f));  // 1e7^(-i/32)
    float c, s;
    sincosf(fr, &s, &c);
    if (d < 32)
      outv = buf[d] * c - buf[d + 32] * s;
    else
      outv = buf[d] * c + buf[d - 32] * s;
  } else {
    outv = buf[d];
  }
  if (h < NH_SZ) {
    ((unsigned*)qbuf)[((long)t * NH_SZ + h) * 256 + d] = pack_hilo(outv);
  } else {
    int kv = h - NH_SZ;
    long ktt = t >> 6, r = t & 63;
    int c = d >> 3, e = d & 7;
    ksw[((((long)kv * 64 + ktt) * 32 + c) * 64 + r) * 8 + e] = __float2bfloat16(outv);
  }
}

// ------------------------------------------------------- flash causal attention
// Q packed hi/lo (T,16,256); Ksw/Vsw swizzled bf16; gate bf16.
// Output packed hi/lo written IN-PLACE over Q buffer.
// Fixed-max softmax (no running max / no rescale); per-lane partial l reduced
// once in epilogue. Rotated barrier schedule: V-prefetch overlaps QK,
// K-prefetch overlaps softmax+PV.
__global__ __launch_bounds__(256) void attn_kernel(unsigned* __restrict__ Qp,
                                                   const __hip_bfloat16* __restrict__ Ksw,
                                                   const __hip_bfloat16* __restrict__ Vsw,
                                                   const __hip_bfloat16* __restrict__ Gt) {
  const int p = blockIdx.x, h = blockIdx.y, kvh = h >> 3;
  const int tid = threadIdx.x, wid = tid >> 6, lane = tid & 63;
  const int lo = lane & 15, quad = lane >> 4;
  __shared__ __align__(16) __hip_bfloat16 Ks[32 * 512];   // [chunk=hd/8][kv=64][8]
  __shared__ __align__(16) __hip_bfloat16 Vs[8 * 2048];   // [chunk=kv/8][hd=256][8]
  __shared__ __align__(16) __hip_bfloat16 Ps[4][16 * 72]; // per-wave, stride 72

  __hip_bfloat16* myP = &Ps[wid][0];
  const f32x4 z4 = {0.f, 0.f, 0.f, 0.f};

  for (int side = 0; side < 2; ++side) {
    const int qt = side ? 63 - p : p;

    // Q fragments hi+lo (A-layout): row = lane&15, k = quad*8 + kc*32 + j
    bf16x8 qh[8], ql[8];
    {
      const unsigned* qp =
          Qp + ((long)(qt * 64 + wid * 16 + lo) * NH_SZ + h) * 256 + quad * 8;
#pragma unroll
      for (int kc = 0; kc < 8; ++kc) {
        uint4 p0 = *(const uint4*)(qp + kc * 32);
        uint4 p1 = *(const uint4*)(qp + kc * 32 + 4);
        bf16x8 a, b;
        a[0] = (short)(p0.x & 0xffff); b[0] = (short)(p0.x >> 16);
        a[1] = (short)(p0.y & 0xffff); b[1] = (short)(p0.y >> 16);
        a[2] = (short)(p0.z & 0xffff); b[2] = (short)(p0.z >> 16);
        a[3] = (short)(p0.w & 0xffff); b[3] = (short)(p0.w >> 16);
        a[4] = (short)(p1.x & 0xffff); b[4] = (short)(p1.x >> 16);
        a[5] = (short)(p1.y & 0xffff); b[5] = (short)(p1.y >> 16);
        a[6] = (short)(p1.z & 0xffff); b[6] = (short)(p1.z >> 16);
        a[7] = (short)(p1.w & 0xffff); b[7] = (short)(p1.w >> 16);
        qh[kc] = a; ql[kc] = b;
      }
    }

    f32x4 acc[16];
#pragma unroll
    for (int od = 0; od < 16; ++od) acc[od] = z4;
    float lsum[4];
#pragma unroll
    for (int r = 0; r < 4; ++r) lsum[r] = 0.f;

    const int qrow_g = qt * 64 + wid * 16 + quad * 4;
    const __hip_bfloat16* kbase = Ksw + (long)kvh * 64 * 16384;
    const __hip_bfloat16* vbase = Vsw + (long)kvh * 64 * 16384;

    // prime: stage K(0), V(0)
#pragma unroll
    for (int j = 0; j < 8; ++j) {
      int c = j * 4 + wid;
      async16(kbase + c * 512 + lane * 8, Ks + c * 512 + lane * 8);
      async16(vbase + c * 512 + lane * 8, Vs + c * 512 + lane * 8);
    }
    __syncthreads();  // drain K(0), V(0)

    for (int kt = 0; kt <= qt; ++kt) {
      // ---- QK: 2-pass (Q_hi + Q_lo) x K(kt)
      f32x4 s[4];
#pragma unroll
      for (int ni = 0; ni < 4; ++ni) s[ni] = z4;
#pragma unroll
      for (int kc = 0; kc < 8; ++kc) {
        bf16x8 ah = qh[kc], al = ql[kc];
#pragma unroll
        for (int ni = 0; ni < 4; ++ni) {
          bf16x8 b = *(const bf16x8*)(Ks + (kc * 4 + quad) * 512 + (ni * 16 + lo) * 8);
          s[ni] = MFMA16(ah, b, s[ni]);
          s[ni] = MFMA16(al, b, s[ni]);
        }
      }
      __syncthreads();  // B: Ks(kt) reads done; drains V(kt) prefetch
      if (kt < qt) {    // K(kt+1) prefetch overlaps softmax+PV
        const __hip_bfloat16* kb = kbase + (long)(kt + 1) * 16384;
#pragma unroll
        for (int j = 0; j < 8; ++j) {
          int c = j * 4 + wid;
          async16(kb + c * 512 + lane * 8, Ks + c * 512 + lane * 8);
        }
      }
      // ---- fixed-max softmax: e = exp(s*scale - M); mask only diagonal tile
      float sv[4][4];
      if (kt == qt) {
#pragma unroll
        for (int ni = 0; ni < 4; ++ni) {
          int kcol = kt * 64 + ni * 16 + lo;
#pragma unroll
          for (int r = 0; r < 4; ++r) {
            float e = __expf(fmaf(s[ni][r], ATT_SCALE, -SOFT_M));
            sv[ni][r] = (kcol > qrow_g + r) ? 0.f : e;
          }
        }
      } else {
#pragma unroll
        for (int ni = 0; ni < 4; ++ni)
#pragma unroll
          for (int r = 0; r < 4; ++r)
            sv[ni][r] = __expf(fmaf(s[ni][r], ATT_SCALE, -SOFT_M));
      }
#pragma unroll
      for (int r = 0; r < 4; ++r)
        lsum[r] += (sv[0][r] + sv[1][r]) + (sv[2][r] + sv[3][r]);
      // write P to own-wave LDS (per-wave buffer: no extra barrier)
#pragma unroll
      for (int ni = 0; ni < 4; ++ni)
#pragma unroll
        for (int r = 0; r < 4; ++r)
          myP[(quad * 4 + r) * 72 + ni * 16 + lo] = __float2bfloat16(sv[ni][r]);
      // ---- O += P V(kt)
#pragma unroll
      for (int kc2 = 0; kc2 < 2; ++kc2) {
        bf16x8 ap = *(const bf16x8*)(myP + lo * 72 + kc2 * 32 + quad * 8);
#pragma unroll
        for (int od = 0; od < 16; ++od) {
          bf16x8 bv = *(const bf16x8*)(Vs + (kc2 * 4 + quad) * 2048 + (od * 16 + lo) * 8);
          acc[od] = MFMA16(ap, bv, acc[od]);
        }
      }
      __syncthreads();  // C: Vs(kt) reads done; drains K(kt+1) prefetch
      if (kt < qt) {    // V(kt+1) prefetch overlaps next QK
        const __hip_bfloat16* vb = vbase + (long)(kt + 1) * 16384;
#pragma unroll
        for (int j = 0; j < 8; ++j) {
          int c = j * 4 + wid;
          async16(vb + c * 512 + lane * 8, Vs + c * 512 + lane * 8);
        }
      }
    }

    // epilogue: reduce l across the 16 lo-lanes (once), then scale + gate
    float l_r[4];
#pragma unroll
    for (int r = 0; r < 4; ++r) {
      float su = lsum[r];
#pragma unroll
      for (int off = 1; off < 16; off <<= 1) su += __shfl_xor(su, off);
      l_r[r] = su;
    }
#pragma unroll
    for (int od = 0; od < 16; ++od)
#pragma unroll
      for (int r = 0; r < 4; ++r) {
        int trow = qt * 64 + wid * 16 + quad * 4 + r;
        int col = od * 16 + lo;
        long idx = ((long)trow * NH_SZ + h) * 256 + col;
        float g = __bfloat162float(Gt[idx]);
        float sig = 1.0f / (1.0f + expf(-g));
        float v = (acc[od][r] / l_r[r]) * sig;
        Qp[idx] = pack_hilo(v);
      }
  }
}

// ------------------- out GEMM: A packed hi/lo (2-pass), B bf16, fp32 out
__global__ __launch_bounds__(256) void gemm_out(const unsigned* __restrict__ Ap,
                                                const __hip_bfloat16* __restrict__ Bt,
                                                float* __restrict__ C,
                                                int M, int N, int K) {
  __shared__ __align__(16) __hip_bfloat16 Ash[128 * 32];
  __shared__ __align__(16) __hip_bfloat16 Asl[128 * 32];
  __shared__ __align__(16) __hip_bfloat16 Bs[128 * 32];
  const int tid = threadIdx.x;
  const int wid = tid >> 6, lane = tid & 63;
  const int lo = lane & 15, quad = lane >> 4;
  const long m0 = (long)blockIdx.y * 128, n0 = (long)blockIdx.x * 128;
  const int wm = (wid >> 1) * 64, wn = (wid & 1) * 64;
  const f32x4 z4 = {0.f, 0.f, 0.f, 0.f};
  f32x4 acc[4][4];
#pragma unroll
  for (int i = 0; i < 4; ++i)
#pragma unroll
    for (int j = 0; j < 4; ++j) acc[i][j] = z4;

  const int cf0 = tid, cf1 = 256 + tid;
  const int br0 = cf0 >> 2, bc0 = (cf0 & 3) * 8;
  const int br1 = cf1 >> 2, bc1 = (cf1 & 3) * 8;
  const __hip_bfloat16* b0 = Bt + (n0 + br0) * K + bc0;
  const __hip_bfloat16* b1 = Bt + (n0 + br1) * K + bc1;

  for (int k0 = 0; k0 < K; k0 += 32) {
    async16(b0 + k0, Bs + cf0 * 8);
    async16(b1 + k0, Bs + cf1 * 8);
#pragma unroll
    for (int it = 0; it < 4; ++it) {
      int c = it * 256 + tid, row = c >> 3, c4 = (c & 7) * 4;
      uint4 p = *(const uint4*)(Ap + (m0 + row) * K + k0 + c4);
      uint2 wh, wl;
      wh.x = (p.x & 0xffff) | ((p.y & 0xffff) << 16);
      wh.y = (p.z & 0xffff) | ((p.w & 0xffff) << 16);
      wl.x = (p.x >> 16) | (p.y & 0xffff0000u);
      wl.y = (p.z >> 16) | (p.w & 0xffff0000u);
      *(uint2*)(Ash + row * 32 + c4) = wh;
      *(uint2*)(Asl + row * 32 + c4) = wl;
    }
    __syncthreads();
    bf16x8 ah[4], al[4], bf[4];
#pragma unroll
    for (int i = 0; i < 4; ++i) {
      ah[i] = *(const bf16x8*)(Ash + (wm + i * 16 + lo) * 32 + quad * 8);
      al[i] = *(const bf16x8*)(Asl + (wm + i * 16 + lo) * 32 + quad * 8);
      bf[i] = *(const bf16x8*)(Bs + (wn + i * 16 + lo) * 32 + quad * 8);
    }
#pragma unroll
    for (int i = 0; i < 4; ++i)
#pragma unroll
      for (int j = 0; j < 4; ++j) {
        acc[i][j] = MFMA16(ah[i], bf[j], acc[i][j]);
        acc[i][j] = MFMA16(al[i], bf[j], acc[i][j]);
      }
    __syncthreads();
  }
#pragma unroll
  for (int i = 0; i < 4; ++i)
#pragma unroll
    for (int j = 0; j < 4; ++j)
#pragma unroll
      for (int r = 0; r < 4; ++r) {
        long row = m0 + wm + i * 16 + quad * 4 + r;
        long col = n0 + wn + j * 16 + lo;
        C[row * N + col] = acc[i][j][r];
      }
}

// ------------------------------------------------------------------- launcher
extern "C" void kernel_launch(void* const* d_in, const int* in_sizes, int n_in,
                              void* d_out, int out_size, void* d_ws, size_t ws_size,
                              hipStream_t stream) {
  (void)in_sizes; (void)n_in; (void)out_size; (void)ws_size;
  const int* positions = (const int*)d_in[0];
  const float* hidden = (const float*)d_in[1];
  const float* Wq = (const float*)d_in[2];
  const float* Wk = (const float*)d_in[3];
  const float* Wv = (const float*)d_in[4];
  const float* Wo = (const float*)d_in[5];
  const float* qw = (const float*)d_in[6];
  const float* kw = (const float*)d_in[7];
  float* out = (float*)d_out;
  char* ws = (char*)d_ws;

  // layout (bytes), total exactly 160 MiB:
  __hip_bfloat16* hid  = (__hip_bfloat16*)(ws + 0);           // 16 MB (dead after GEMMs)
  __hip_bfloat16* WqT  = (__hip_bfloat16*)(ws + 16777216);    // 32 MB
  __hip_bfloat16* WkT  = (__hip_bfloat16*)(ws + 50331648);    //  2 MB
  __hip_bfloat16* WvT  = (__hip_bfloat16*)(ws + 52428800);    //  2 MB
  float*          qf   = (float*)(ws + 54525952);             // 64 MB fp32 q -> packed -> o packed
  __hip_bfloat16* gate = (__hip_bfloat16*)(ws + 121634816);   // 32 MB (T,16,256)
  float*          kf   = (float*)(ws + 155189248);            //  8 MB (T,2,256) fp32
  __hip_bfloat16* vraw = (__hip_bfloat16*)(ws + 163577856);   //  4 MB -> end 167,772,160
  __hip_bfloat16* Ksw  = WkT;                                  // alias 4 MB [WkT+WvT] after k/v GEMMs
  __hip_bfloat16* Vsw  = hid;                                  // alias 4 MB of hid after GEMMs
  __hip_bfloat16* WoT  = gate;                                 // alias gate region after attn
  unsigned* qpk = (unsigned*)qf;

  // 1) casts / transposes
  cast_f32_bf16<<<dim3(8192), dim3(256), 0, stream>>>(hidden, hid, 2097152);
  transpose_cast<float><<<dim3(256, 64), dim3(256), 0, stream>>>(Wq, WqT, 2048, 8192);
  transpose_cast<float><<<dim3(16, 64), dim3(256), 0, stream>>>(Wk, WkT, 2048, 512);
  transpose_cast<float><<<dim3(16, 64), dim3(256), 0, stream>>>(Wv, WvT, 2048, 512);
  // 2) projections: q fp32 + gate bf16; k fp32; v bf16
  gemm_qg<<<dim3(64, 32), dim3(256), 0, stream>>>(hid, WqT, qf, gate, 4096, 8192, 2048);
  gemm_bt<1><<<dim3(4, 32), dim3(256), 0, stream>>>(hid, WkT, kf, 4096, 512, 2048);
  gemm_bt<0><<<dim3(4, 32), dim3(256), 0, stream>>>(hid, WvT, vraw, 4096, 512, 2048);
  // 3) V -> swizzled (after GEMMs: Vsw aliases hid)
  v_swizzle<<<dim3(64, 2), dim3(256), 0, stream>>>(vraw, Vsw);
  // 4) RMSNorm + RoPE: q packed hi/lo in-place; k swizzled bf16 -> Ksw
  norm_rope_pack<<<dim3(4096, 18), dim3(256), 0, stream>>>(qf, kf, Ksw, positions, qw, kw);
  // 5) flash attention (balanced q-tile pairs); writes o packed hi/lo over q buffer
  attn_kernel<<<dim3(32, 16), dim3(256), 0, stream>>>(qpk, Ksw, Vsw, gate);
  // 6) Wo -> bf16 transpose (into dead gate region), then 2-pass out GEMM
  transpose_cast<float><<<dim3(64, 128), dim3(256), 0, stream>>>(Wo, WoT, 4096, 2048);
  gemm_out<<<dim3(16, 32), dim3(256), 0, stream>>>(qpk, WoT, out, 4096, 2048, 4096);
}